// Round 13
// baseline (165.351 us; speedup 1.0000x reference)
//
#include <hip/hip_runtime.h>

#define Bn 512
#define Kn 160
#define Hn 256
#define BK (Bn*Kn)
#define NBF 25600   // per-batch 160*160 bf16 elements
#define ALPHA 0.5f
#define MAX_SPAN 30
#define L_FGW 0.1f
#define L_SPAN 0.5f
#define L_CONS 0.3f
#define KP 16
#define NP 10

typedef __bf16 bf16x8 __attribute__((ext_vector_type(8)));
typedef float f32x16 __attribute__((ext_vector_type(16)));
typedef float f32x4v __attribute__((ext_vector_type(4)));
typedef unsigned short ushort;
typedef unsigned int uint;

__device__ __forceinline__ ushort b16(float f) {
  __bf16 t = (__bf16)f;
  return *(ushort*)&t;
}

// raw barrier: LDS drained, global loads stay in flight (no vmcnt drain)
__device__ __forceinline__ void wg_barrier() {
  asm volatile("s_waitcnt lgkmcnt(0)" ::: "memory");
  __builtin_amdgcn_s_barrier();
  __builtin_amdgcn_sched_barrier(0);
}

// ---- QA head logits: one wave per (emb,row); en/vi non-temporal (dead after).
// First 640 blocks also zero the q/vsc accumulation buffers (2*BK floats).
__global__ __launch_bounds__(256) void qa_logits_k(
    const float* __restrict__ en, const float* __restrict__ vi,
    const float* __restrict__ w_s, const float* __restrict__ b_s,
    const float* __restrict__ w_e, const float* __restrict__ b_e,
    float* __restrict__ wsl, float* __restrict__ qvsc_zero) {
  if (blockIdx.x < 640)
    qvsc_zero[(size_t)blockIdx.x * 256 + threadIdx.x] = 0.f;
  int row = blockIdx.x * 4 + (threadIdx.x >> 6);
  int lane = threadIdx.x & 63;
  bool isVi = row >= BK;
  int r = isVi ? row - BK : row;
  const float* emb = isVi ? vi : en;
  f32x4v v = __builtin_nontemporal_load((const f32x4v*)(emb + (size_t)r * Hn + lane * 4));
  float4 a = *(const float4*)(w_s + lane * 4);
  float4 c = *(const float4*)(w_e + lane * 4);
  float ds = v[0]*a.x + v[1]*a.y + v[2]*a.z + v[3]*a.w;
  float de = v[0]*c.x + v[1]*c.y + v[2]*c.z + v[3]*c.w;
  #pragma unroll
  for (int o = 32; o; o >>= 1) { ds += __shfl_xor(ds, o); de += __shfl_xor(de, o); }
  if (lane == 0) {
    size_t base = isVi ? (size_t)2 * BK : 0;
    wsl[base + r] = ds + b_s[0];
    wsl[base + BK + r] = de + b_e[0];
  }
}

// ---- gamma/M float4 pass, 2 blocks/batch (80-row halves), 640 threads ----
// Emits: p (deferred LDS reduce), q/vsc (global atomics), w, AND bf16 copies
// gbf (row-major, direct stores) + gtbf (transposed via LDS tile).
__global__ __launch_bounds__(640) void stats_part_k(
    const float* __restrict__ gam, const float* __restrict__ M,
    const int* __restrict__ enst, const int* __restrict__ enen,
    float* __restrict__ p_arr, float* __restrict__ q_arr,
    float* __restrict__ vsc_arr, float* __restrict__ wpart,
    ushort* __restrict__ gbf, ushort* __restrict__ gtbf) {
  __shared__ float prow[5][16][41];
  __shared__ ushort gt[80][162];
  __shared__ float qsh[Kn];
  __shared__ float vsh[Kn];
  __shared__ float wsh[10];
  int bid = blockIdx.x;
  int b = bid >> 1;
  int r0 = (bid & 1) * 80;
  int tid = threadIdx.x;
  int rm = tid / 40;
  int c = tid - 40 * rm;
  int wv = tid >> 6, lane = tid & 63;
  for (int t = tid; t < Kn; t += 640) { qsh[t] = 0.f; vsh[t] = 0.f; }
  __syncthreads();
  int s0 = enst[b], e0 = enen[b];
  int s = min(max(s0, 0), Kn - 1);
  int e = max(s, min(max(e0, 0), Kn - 1));
  const float* gb = gam + (size_t)b * Kn * Kn + (size_t)r0 * Kn;
  const float* mb = M + (size_t)b * Kn * Kn + (size_t)r0 * Kn;
  float q4[4] = {0.f, 0.f, 0.f, 0.f};
  float v4[4] = {0.f, 0.f, 0.f, 0.f};
  float rp[5];
  float wloc = 0.f;
  #pragma unroll
  for (int k = 0; k < 5; ++k) {
    int lr = 16 * k + rm;
    f32x4v g = __builtin_nontemporal_load((const f32x4v*)(gb + (size_t)lr * Kn + 4 * c));
    f32x4v m = __builtin_nontemporal_load((const f32x4v*)(mb + (size_t)lr * Kn + 4 * c));
    wloc += m[0]*g[0] + m[1]*g[1] + m[2]*g[2] + m[3]*g[3];
    rp[k] = g[0] + g[1] + g[2] + g[3];
    q4[0] += g[0]; q4[1] += g[1]; q4[2] += g[2]; q4[3] += g[3];
    int i = r0 + lr;
    float f = (i >= s && i <= e) ? 1.f : 0.f;
    v4[0] += f*g[0]; v4[1] += f*g[1]; v4[2] += f*g[2]; v4[3] += f*g[3];
    // bf16 copies
    ushort u0 = b16(g[0]), u1 = b16(g[1]), u2 = b16(g[2]), u3 = b16(g[3]);
    gt[lr][4*c] = u0; gt[lr][4*c+1] = u1; gt[lr][4*c+2] = u2; gt[lr][4*c+3] = u3;
    uint2 pk;
    pk.x = (uint)u0 | ((uint)u1 << 16);
    pk.y = (uint)u2 | ((uint)u3 << 16);
    *(uint2*)(gbf + (size_t)b * NBF + (size_t)(r0 + lr) * 160 + 4 * c) = pk;
  }
  // ---- deferred reductions ----
  #pragma unroll
  for (int k = 0; k < 5; ++k) prow[k][rm][c] = rp[k];
  #pragma unroll
  for (int j = 0; j < 4; ++j) {
    atomicAdd(&qsh[4 * c + j], q4[j]);
    atomicAdd(&vsh[4 * c + j], v4[j]);
  }
  #pragma unroll
  for (int o = 32; o; o >>= 1) wloc += __shfl_xor(wloc, o);
  if (lane == 0) wsh[wv] = wloc;
  __syncthreads();
  if (tid < 80) {
    int k = tid >> 4, rm2 = tid & 15;
    float srow = 0.f;
    #pragma unroll 8
    for (int c2 = 0; c2 < 40; ++c2) srow += prow[k][rm2][c2];
    p_arr[(size_t)b * Kn + r0 + tid] = srow;
  }
  if (tid < Kn) {
    atomicAdd(&q_arr[(size_t)b * Kn + tid], qsh[tid]);
    atomicAdd(&vsc_arr[(size_t)b * Kn + tid], vsh[tid]);
  }
  if (tid == 0) {
    float sw = 0.f;
    #pragma unroll
    for (int i2 = 0; i2 < 10; ++i2) sw += wsh[i2];
    wpart[bid] = sw;
  }
  // ---- gtbf (gamma^T) write-out: gtbf[j][k] = gamma[k][j] ----
  #pragma unroll
  for (int i = 0; i < 10; ++i) {
    int u = tid + 640 * i;          // u < 6400
    int j = u / 40;
    int ku = u - 40 * j;
    uint v = (uint)gt[2 * ku][j] | ((uint)gt[2 * ku + 1][j] << 16);
    *(uint*)(gtbf + (size_t)b * NBF + (size_t)j * 160 + r0 + 2 * ku) = v;
  }
}

// ---- gw1/gw2 over D_en/D_vi (float4, nt) + bf16 emits dbf/vtbf;
// even blocks also run combine (span decode + QA CE + KL + span CE). ----
__global__ __launch_bounds__(640) void dpass_k(
    const float* __restrict__ Den, const float* __restrict__ Dvi,
    const int* __restrict__ enst, const int* __restrict__ enen,
    const float* __restrict__ p_arr, const float* __restrict__ q_arr,
    const float* __restrict__ vsc_arr, const float* __restrict__ wpart,
    const float* __restrict__ wsl, float* __restrict__ g12part,
    float* __restrict__ sp1, ushort* __restrict__ dbf, ushort* __restrict__ vtbf) {
  __shared__ float p_s[Kn];
  __shared__ float q_s[Kn];
  __shared__ float red[20];
  __shared__ ushort vt[80][162];
  __shared__ float vsc_l[Kn];
  __shared__ float bv[256];
  __shared__ int bidx[256];
  __shared__ int pspe[2];
  int bid = blockIdx.x;
  int b = bid >> 1;
  int r0 = (bid & 1) * 80;
  int tid = threadIdx.x;
  int rm = tid / 40;
  int c = tid - 40 * rm;
  int wv = tid >> 6, lane = tid & 63;
  if (tid < Kn) {
    p_s[tid] = p_arr[(size_t)b * Kn + tid];
    q_s[tid] = q_arr[(size_t)b * Kn + tid];
  }
  __syncthreads();
  const float* db = Den + (size_t)b * Kn * Kn + (size_t)r0 * Kn;
  const float* vb = Dvi + (size_t)b * Kn * Kn + (size_t)r0 * Kn;
  float pc0 = p_s[4*c], pc1 = p_s[4*c+1], pc2 = p_s[4*c+2], pc3 = p_s[4*c+3];
  float qc0 = q_s[4*c], qc1 = q_s[4*c+1], qc2 = q_s[4*c+2], qc3 = q_s[4*c+3];
  float g1loc = 0.f, g2loc = 0.f;
  #pragma unroll
  for (int k = 0; k < 5; ++k) {
    int lr = 16 * k + rm;
    int i = r0 + lr;
    f32x4v d = __builtin_nontemporal_load((const f32x4v*)(db + (size_t)lr * Kn + 4 * c));
    g1loc += p_s[i] * (d[0]*d[0]*pc0 + d[1]*d[1]*pc1 + d[2]*d[2]*pc2 + d[3]*d[3]*pc3);
    uint2 pk;
    pk.x = (uint)b16(d[0]) | ((uint)b16(d[1]) << 16);
    pk.y = (uint)b16(d[2]) | ((uint)b16(d[3]) << 16);
    *(uint2*)(dbf + (size_t)b * NBF + (size_t)i * 160 + 4 * c) = pk;
    f32x4v v = __builtin_nontemporal_load((const f32x4v*)(vb + (size_t)lr * Kn + 4 * c));
    g2loc += q_s[i] * (v[0]*v[0]*qc0 + v[1]*v[1]*qc1 + v[2]*v[2]*qc2 + v[3]*v[3]*qc3);
    vt[lr][4*c] = b16(v[0]); vt[lr][4*c+1] = b16(v[1]);
    vt[lr][4*c+2] = b16(v[2]); vt[lr][4*c+3] = b16(v[3]);
  }
  #pragma unroll
  for (int o = 32; o; o >>= 1) { g1loc += __shfl_xor(g1loc, o); g2loc += __shfl_xor(g2loc, o); }
  if (lane == 0) { red[wv] = g1loc; red[10 + wv] = g2loc; }
  __syncthreads();
  if (tid == 0) {
    float s1 = 0.f, s2 = 0.f;
    #pragma unroll
    for (int i = 0; i < 10; ++i) { s1 += red[i]; s2 += red[10 + i]; }
    g12part[(size_t)bid * 2] = s1;
    g12part[(size_t)bid * 2 + 1] = s2;
  }
  // ---- vtbf (D_vi^T) write-out ----
  #pragma unroll
  for (int i = 0; i < 10; ++i) {
    int u = tid + 640 * i;
    int j = u / 40;
    int ku = u - 40 * j;
    uint v = (uint)vt[2 * ku][j] | ((uint)vt[2 * ku + 1][j] << 16);
    *(uint*)(vtbf + (size_t)b * NBF + (size_t)j * 160 + r0 + 2 * ku) = v;
  }
  // ---- combine tail (even blocks only; whole block branches uniformly) ----
  if ((bid & 1) != 0) return;
  int s0 = enst[b], e0 = enen[b];
  if (tid < Kn) vsc_l[tid] = vsc_arr[(size_t)b * Kn + tid];
  if (tid == 0)
    sp1[(size_t)b * 12 + 4] = wpart[2 * b] + wpart[2 * b + 1];
  __syncthreads();
  float best = -1e30f;
  int bfl = 0x7fffffff;
  if (tid < Kn) {
    float vsi = vsc_l[tid];
    int hi = min(tid + MAX_SPAN, Kn - 1);
    for (int ei = tid; ei <= hi; ++ei) {
      float v = vsi + vsc_l[ei];
      if (v > best) { best = v; bfl = tid * Kn + ei; }  // first-max (np.argmax)
    }
  }
  if (tid < 256) { bv[tid] = best; bidx[tid] = bfl; }
  for (int st = 128; st > 0; st >>= 1) {
    __syncthreads();
    if (tid < st) {
      float v2 = bv[tid + st]; int i2 = bidx[tid + st];
      if (v2 > bv[tid] || (v2 == bv[tid] && i2 < bidx[tid])) { bv[tid] = v2; bidx[tid] = i2; }
    }
  }
  if (tid == 0) {
    int fl = bidx[0];
    int ps = fl / Kn, pe = fl - (fl / Kn) * Kn;
    if (s0 == 0 && e0 == 0) { ps = 0; pe = 0; }
    pspe[0] = ps; pspe[1] = pe;
  }
  __syncthreads();
  if (wv == 0) {
    const float* es = wsl + (size_t)b * Kn;
    const float* ee = wsl + (size_t)BK + (size_t)b * Kn;
    const float* vs = wsl + (size_t)2 * BK + (size_t)b * Kn;
    const float* ve = wsl + (size_t)3 * BK + (size_t)b * Kn;
    float xes[3], xee[3], xvs[3], xve[3];
    #pragma unroll
    for (int j = 0; j < 3; ++j) {
      int idx = lane + 64 * j;
      bool val = idx < Kn;
      xes[j] = val ? es[idx] : -1e30f;
      xee[j] = val ? ee[idx] : -1e30f;
      xvs[j] = val ? vs[idx] : -1e30f;
      xve[j] = val ? ve[idx] : -1e30f;
    }
    auto wlse = [&](float x0, float x1, float x2) -> float {
      float m = fmaxf(fmaxf(x0, x1), x2);
      #pragma unroll
      for (int o = 32; o; o >>= 1) m = fmaxf(m, __shfl_xor(m, o));
      float su = expf(x0 - m) + expf(x1 - m) + expf(x2 - m);
      #pragma unroll
      for (int o = 32; o; o >>= 1) su += __shfl_xor(su, o);
      return m + logf(su);
    };
    float l_es = wlse(xes[0], xes[1], xes[2]);
    float l_ee = wlse(xee[0], xee[1], xee[2]);
    float l_vs = wlse(xvs[0], xvs[1], xvs[2]);
    float l_ve = wlse(xve[0], xve[1], xve[2]);
    float lT_es = wlse(xes[0]*0.5f, xes[1]*0.5f, xes[2]*0.5f);
    float lT_ee = wlse(xee[0]*0.5f, xee[1]*0.5f, xee[2]*0.5f);
    float lT_vs = wlse(xvs[0]*0.5f, xvs[1]*0.5f, xvs[2]*0.5f);
    float lT_ve = wlse(xve[0]*0.5f, xve[1]*0.5f, xve[2]*0.5f);
    float kls = 0.f, kle = 0.f;
    #pragma unroll
    for (int j = 0; j < 3; ++j) {
      int idx = lane + 64 * j;
      if (idx < Kn) {
        float aa = xes[j]*0.5f - lT_es;
        float bb = xvs[j]*0.5f - lT_vs;
        kls += expf(aa) * (aa - bb);
        float cc = xee[j]*0.5f - lT_ee;
        float dd = xve[j]*0.5f - lT_ve;
        kle += expf(cc) * (cc - dd);
      }
    }
    #pragma unroll
    for (int o = 32; o; o >>= 1) { kls += __shfl_xor(kls, o); kle += __shfl_xor(kle, o); }
    if (lane == 0) {
      int sl = min(max(s0, 0), Kn - 1);
      int el = min(max(e0, 0), Kn - 1);
      float* o = sp1 + (size_t)b * 12;
      o[0] = l_es - es[sl];
      o[1] = l_ee - ee[el];
      o[2] = kls;
      o[3] = kle;
      bool answerable = (s0 > 0) || (e0 > 0);
      float ce = 0.5f * ((l_vs - vs[pspe[0]]) + (l_ve - ve[pspe[1]]));
      o[5] = answerable ? ce : 0.f;
      o[6] = answerable ? 1.f : 0.f;
    }
  }
}

// ---- MFMA FGW, pure gw3. All operands pre-converted bf16 (L2/L3-resident):
// one 16B load + one 16B ds_write per fragment, no cvt, no strided loads.
// Software-pipelined, raw lgkm-only barriers. 2 blocks/batch (column halves).
__global__ __launch_bounds__(512) void fgw_k(
    const ushort* __restrict__ dbf, const ushort* __restrict__ gbf,
    const ushort* __restrict__ gtbf, const ushort* __restrict__ vtbf,
    float* __restrict__ sp2) {
  __shared__ __align__(16) __bf16 sDen[2][2][Kn][8];
  __shared__ __align__(16) __bf16 sG  [2][2][Kn][8];
  __shared__ __align__(16) __bf16 sGT [2][2][96][8];
  __shared__ __align__(16) __bf16 sVT [2][2][96][8];
  __shared__ float red[8];
  int bid = blockIdx.x;
  int h = (bid >> 3) & 1;
  int b = ((bid >> 4) << 3) | (bid & 7);
  const int JB = h ? 96 : 0;
  const int NBJ = h ? 64 : 96;
  const int NTJ = h ? 2 : 3;
  const int NT = 5 * NTJ;
  int tid = threadIdx.x;
  int wid = tid >> 6, lane = tid & 63;

  // slot0: frag = tid. tid<320 -> Den(c,r); tid in [320,512) -> G frag f=tid-320.
  const ushort* s0p;
  __bf16 *d00, *d01;
  {
    int isG = tid >= 320 ? 1 : 0;
    int f = tid - 320 * isG;
    int cc = f >= 160 ? 1 : 0;
    int r = f - 160 * cc;
    s0p = (isG ? gbf : dbf) + (size_t)b * NBF + (size_t)r * 160 + 8 * cc;
    d00 = isG ? &sG[0][cc][r][0] : &sDen[0][cc][r][0];
    d01 = isG ? &sG[1][cc][r][0] : &sDen[1][cc][r][0];
  }
  // slot1: frag = 512+tid. tid<128 -> G frag 192+tid (c=1, r=tid+32);
  // else B-side frag fb=tid-128: GT (fb<2*NBJ) then VT.
  bool act1 = true;
  const ushort* s1p = gbf;
  __bf16 *d10 = &sGT[0][0][0][0], *d11 = &sGT[1][0][0][0];
  if (tid < 128) {
    int r = tid + 32;
    s1p = gbf + (size_t)b * NBF + (size_t)r * 160 + 8;
    d10 = &sG[0][1][r][0];
    d11 = &sG[1][1][r][0];
  } else {
    int fb = tid - 128;
    act1 = fb < 4 * NBJ;
    if (act1) {
      int op1 = fb >= 2 * NBJ ? 1 : 0;
      int t2 = fb - 2 * NBJ * op1;
      int c1 = t2 >= NBJ ? 1 : 0;
      int r1 = t2 - NBJ * c1;
      int j = JB + r1;
      s1p = (op1 ? vtbf : gtbf) + (size_t)b * NBF + (size_t)j * 160 + 8 * c1;
      d10 = op1 ? &sVT[0][c1][r1][0] : &sGT[0][c1][r1][0];
      d11 = op1 ? &sVT[1][c1][r1][0] : &sGT[1][c1][r1][0];
    }
  }
  bf16x8 vA0, vA1, vB0, vB1;
  auto load0 = [&](int p, bf16x8& v) { v = *(const bf16x8*)(s0p + p * KP); };
  auto load1 = [&](int p, bf16x8& v) { if (act1) v = *(const bf16x8*)(s1p + p * KP); };
  auto wr = [&](bf16x8 v0, bf16x8 v1, __bf16* w0, __bf16* w1) {
    *(bf16x8*)w0 = v0;
    if (act1) *(bf16x8*)w1 = v1;
  };

  int ra = lane & 31, cc2 = lane >> 5;
  int t1i = wid + 8;
  bool val1t = t1i < NT;
  int ti0 = wid / NTJ, tj0 = wid - ti0 * NTJ;
  int rowa0 = ti0 * 32 + ra, rowb0 = tj0 * 32 + ra;
  int ti1 = t1i / NTJ, tj1 = t1i - ti1 * NTJ;
  int rowa1 = ti1 * 32 + ra, rowb1 = tj1 * 32 + ra;
  f32x16 acc10 = {}, acc20 = {}, acc11 = {}, acc21 = {};
  auto mf = [&](int BUF) {
    {
      bf16x8 a1 = *(const bf16x8*)&sDen[BUF][cc2][rowa0][0];
      bf16x8 b1 = *(const bf16x8*)&sGT[BUF][cc2][rowb0][0];
      bf16x8 a2 = *(const bf16x8*)&sG[BUF][cc2][rowa0][0];
      bf16x8 b2 = *(const bf16x8*)&sVT[BUF][cc2][rowb0][0];
      acc10 = __builtin_amdgcn_mfma_f32_32x32x16_bf16(a1, b1, acc10, 0, 0, 0);
      acc20 = __builtin_amdgcn_mfma_f32_32x32x16_bf16(a2, b2, acc20, 0, 0, 0);
    }
    if (val1t) {
      bf16x8 a1 = *(const bf16x8*)&sDen[BUF][cc2][rowa1][0];
      bf16x8 b1 = *(const bf16x8*)&sGT[BUF][cc2][rowb1][0];
      bf16x8 a2 = *(const bf16x8*)&sG[BUF][cc2][rowa1][0];
      bf16x8 b2 = *(const bf16x8*)&sVT[BUF][cc2][rowb1][0];
      acc11 = __builtin_amdgcn_mfma_f32_32x32x16_bf16(a1, b1, acc11, 0, 0, 0);
      acc21 = __builtin_amdgcn_mfma_f32_32x32x16_bf16(a2, b2, acc21, 0, 0, 0);
    }
  };

  load0(0, vA0); load1(0, vA1);
  load0(1, vB0); load1(1, vB1);
  wr(vA0, vA1, d00, d10);
  __syncthreads();
  for (int p = 0; p < NP; p += 2) {
    if (p + 2 < NP) { load0(p + 2, vA0); load1(p + 2, vA1); }
    mf(0);
    wr(vB0, vB1, d01, d11);
    wg_barrier();
    if (p + 3 < NP) { load0(p + 3, vB0); load1(p + 3, vB1); }
    mf(1);
    if (p + 2 < NP) wr(vA0, vA1, d00, d10);
    wg_barrier();
  }
  float g3 = 0.f;
  #pragma unroll
  for (int r2 = 0; r2 < 16; ++r2) g3 += acc10[r2] * acc20[r2];
  if (val1t) {
    #pragma unroll
    for (int r2 = 0; r2 < 16; ++r2) g3 += acc11[r2] * acc21[r2];
  }
  #pragma unroll
  for (int o = 32; o; o >>= 1) g3 += __shfl_xor(g3, o);
  if (lane == 0) red[wid] = g3;
  __syncthreads();
  if (tid == 0) {
    float s3 = 0.f;
    #pragma unroll
    for (int i = 0; i < 8; ++i) s3 += red[i];
    sp2[bid] = s3;
  }
}

// ---- final reduction of per-block slabs ----
__global__ __launch_bounds__(512) void finalize_k(
    const float* __restrict__ sp1, const float* __restrict__ sp2,
    const float* __restrict__ g12part, float* __restrict__ out) {
  __shared__ float red[8][10];
  int tid = threadIdx.x;
  int wid = tid >> 6, lane = tid & 63;
  float v[10];
  const float* a = sp1 + (size_t)tid * 12;
  #pragma unroll
  for (int i = 0; i < 7; ++i) v[i] = a[i];
  v[7] = g12part[4 * tid] + g12part[4 * tid + 2];
  v[8] = g12part[4 * tid + 1] + g12part[4 * tid + 3];
  v[9] = sp2[2 * tid] + sp2[2 * tid + 1];
  #pragma unroll
  for (int i = 0; i < 10; ++i) {
    float s = v[i];
    #pragma unroll
    for (int o = 32; o; o >>= 1) s += __shfl_xor(s, o);
    v[i] = s;
  }
  if (lane == 0) {
    #pragma unroll
    for (int i = 0; i < 10; ++i) red[wid][i] = v[i];
  }
  __syncthreads();
  if (tid == 0) {
    float t[10];
    #pragma unroll
    for (int i = 0; i < 10; ++i) {
      float s = 0.f;
      #pragma unroll
      for (int w2 = 0; w2 < 8; ++w2) s += red[w2][i];
      t[i] = s;
    }
    float ce_s = t[0], ce_e = t[1], kls = t[2], kle = t[3];
    float w = t[4], spn = t[5], nans = t[6];
    float gw1 = t[7], gw2 = t[8], gw3 = t[9];
    float l_qa = (ce_s + ce_e) / (2.f * Bn);
    float l_fgw = (ALPHA * (gw1 + gw2 - 2.f * gw3) + (1.f - ALPHA) * w) / Bn;
    float l_span = (nans > 0.f) ? spn / fmaxf(nans, 1.f) : 0.f;
    float l_cons = 2.f * (kls + kle) / Bn;  // T^2 * ((kls+kle)/B) / 2 with T=2
    float total = l_qa + L_FGW * l_fgw + L_SPAN * l_span + L_CONS * l_cons;
    out[0] = total; out[1] = l_qa; out[2] = l_fgw; out[3] = l_span; out[4] = l_cons;
  }
}

extern "C" void kernel_launch(void* const* d_in, const int* in_sizes, int n_in,
                              void* d_out, int out_size, void* d_ws, size_t ws_size,
                              hipStream_t stream) {
  const float* en  = (const float*)d_in[0];
  const float* vi  = (const float*)d_in[1];
  const float* gam = (const float*)d_in[2];
  const float* Den = (const float*)d_in[3];
  const float* Dvi = (const float*)d_in[4];
  const float* M   = (const float*)d_in[5];
  const int* enst  = (const int*)d_in[6];
  const int* enen  = (const int*)d_in[7];
  const float* w_s = (const float*)d_in[8];
  const float* b_s = (const float*)d_in[9];
  const float* w_e = (const float*)d_in[10];
  const float* b_e = (const float*)d_in[11];
  float* ws = (float*)d_ws;
  float* wsl = ws;                         // 4*BK logits
  float* p_arr = ws + (size_t)4 * BK;      // BK
  float* q_arr = p_arr + BK;               // BK (atomic-accumulated, zeroed by qa)
  float* vsc_arr = q_arr + BK;             // BK (atomic-accumulated, zeroed by qa)
  float* wpart = vsc_arr + BK;             // 1024
  float* sp1 = wpart + 1024;               // 512*12
  float* sp2 = sp1 + 12 * Bn;              // 1024
  float* g12part = sp2 + 1024;             // 1024*2
  ushort* gbf = (ushort*)(g12part + 2048); // 512*25600 bf16 each:
  ushort* gtbf = gbf + (size_t)Bn * NBF;
  ushort* dbf = gtbf + (size_t)Bn * NBF;
  ushort* vtbf = dbf + (size_t)Bn * NBF;
  float* out = (float*)d_out;

  qa_logits_k<<<(2 * BK) / 4, 256, 0, stream>>>(en, vi, w_s, b_s, w_e, b_e, wsl, q_arr);
  stats_part_k<<<2 * Bn, 640, 0, stream>>>(gam, M, enst, enen, p_arr, q_arr, vsc_arr,
                                           wpart, gbf, gtbf);
  dpass_k<<<2 * Bn, 640, 0, stream>>>(Den, Dvi, enst, enen, p_arr, q_arr, vsc_arr,
                                      wpart, wsl, g12part, sp1, dbf, vtbf);
  fgw_k<<<2 * Bn, 512, 0, stream>>>(dbf, gbf, gtbf, vtbf, sp2);
  finalize_k<<<1, 512, 0, stream>>>(sp1, sp2, g12part, out);
}

// Round 14
// 151.855 us; speedup vs baseline: 1.0889x; 1.0889x over previous
//
#include <hip/hip_runtime.h>

#define Bn 512
#define Kn 160
#define Hn 256
#define BK (Bn*Kn)
#define ALPHA 0.5f
#define MAX_SPAN 30
#define L_FGW 0.1f
#define L_SPAN 0.5f
#define L_CONS 0.3f
#define KP 16
#define NP 10

typedef __bf16 bf16x8 __attribute__((ext_vector_type(8)));
typedef float f32x16 __attribute__((ext_vector_type(16)));
typedef float f32x4v __attribute__((ext_vector_type(4)));

// raw barrier: LDS drained, global loads stay in flight (no vmcnt drain)
__device__ __forceinline__ void wg_barrier() {
  asm volatile("s_waitcnt lgkmcnt(0)" ::: "memory");
  __builtin_amdgcn_s_barrier();
  __builtin_amdgcn_sched_barrier(0);
}

// ---- QA head logits: one wave per (emb,row); en/vi non-temporal (dead after).
// First 640 blocks also zero the q/vsc accumulation buffers (2*BK floats).
__global__ __launch_bounds__(256) void qa_logits_k(
    const float* __restrict__ en, const float* __restrict__ vi,
    const float* __restrict__ w_s, const float* __restrict__ b_s,
    const float* __restrict__ w_e, const float* __restrict__ b_e,
    float* __restrict__ wsl, float* __restrict__ qvsc_zero) {
  if (blockIdx.x < 640)
    qvsc_zero[(size_t)blockIdx.x * 256 + threadIdx.x] = 0.f;
  int row = blockIdx.x * 4 + (threadIdx.x >> 6);
  int lane = threadIdx.x & 63;
  bool isVi = row >= BK;
  int r = isVi ? row - BK : row;
  const float* emb = isVi ? vi : en;
  f32x4v v = __builtin_nontemporal_load((const f32x4v*)(emb + (size_t)r * Hn + lane * 4));
  float4 a = *(const float4*)(w_s + lane * 4);
  float4 c = *(const float4*)(w_e + lane * 4);
  float ds = v[0]*a.x + v[1]*a.y + v[2]*a.z + v[3]*a.w;
  float de = v[0]*c.x + v[1]*c.y + v[2]*c.z + v[3]*c.w;
  #pragma unroll
  for (int o = 32; o; o >>= 1) { ds += __shfl_xor(ds, o); de += __shfl_xor(de, o); }
  if (lane == 0) {
    size_t base = isVi ? (size_t)2 * BK : 0;
    wsl[base + r] = ds + b_s[0];
    wsl[base + BK + r] = de + b_e[0];
  }
}

// ---- gamma/M float4 streaming pass, 2 blocks/batch (80-row halves) ----
// 640 threads = (rm = tid/40, c = tid%40): each k-iter reads a contiguous
// 16-row slab at 16 B/lane, zero divergence. All reductions deferred.
__global__ __launch_bounds__(640) void stats_part_k(
    const float* __restrict__ gam, const float* __restrict__ M,
    const int* __restrict__ enst, const int* __restrict__ enen,
    float* __restrict__ p_arr, float* __restrict__ q_arr,
    float* __restrict__ vsc_arr, float* __restrict__ wpart) {
  __shared__ float prow[5][16][41];
  __shared__ float qsh[Kn];
  __shared__ float vsh[Kn];
  __shared__ float wsh[10];
  int bid = blockIdx.x;
  int b = bid >> 1;
  int r0 = (bid & 1) * 80;
  int tid = threadIdx.x;
  int rm = tid / 40;
  int c = tid - 40 * rm;
  int wv = tid >> 6, lane = tid & 63;
  for (int t = tid; t < Kn; t += 640) { qsh[t] = 0.f; vsh[t] = 0.f; }
  __syncthreads();
  int s0 = enst[b], e0 = enen[b];
  int s = min(max(s0, 0), Kn - 1);
  int e = max(s, min(max(e0, 0), Kn - 1));
  const float* gb = gam + (size_t)b * Kn * Kn + (size_t)r0 * Kn;
  const float* mb = M + (size_t)b * Kn * Kn + (size_t)r0 * Kn;
  float q4[4] = {0.f, 0.f, 0.f, 0.f};
  float v4[4] = {0.f, 0.f, 0.f, 0.f};
  float rp[5];
  float wloc = 0.f;
  #pragma unroll
  for (int k = 0; k < 5; ++k) {
    int lr = 16 * k + rm;
    float4 g = *(const float4*)(gb + (size_t)lr * Kn + 4 * c);
    f32x4v m = __builtin_nontemporal_load((const f32x4v*)(mb + (size_t)lr * Kn + 4 * c));
    wloc += m[0]*g.x + m[1]*g.y + m[2]*g.z + m[3]*g.w;
    rp[k] = g.x + g.y + g.z + g.w;
    q4[0] += g.x; q4[1] += g.y; q4[2] += g.z; q4[3] += g.w;
    int i = r0 + lr;
    float f = (i >= s && i <= e) ? 1.f : 0.f;
    v4[0] += f*g.x; v4[1] += f*g.y; v4[2] += f*g.z; v4[3] += f*g.w;
  }
  // ---- deferred reductions ----
  #pragma unroll
  for (int k = 0; k < 5; ++k) prow[k][rm][c] = rp[k];
  #pragma unroll
  for (int j = 0; j < 4; ++j) {
    atomicAdd(&qsh[4 * c + j], q4[j]);
    atomicAdd(&vsh[4 * c + j], v4[j]);
  }
  #pragma unroll
  for (int o = 32; o; o >>= 1) wloc += __shfl_xor(wloc, o);
  if (lane == 0) wsh[wv] = wloc;
  __syncthreads();
  if (tid < 80) {
    int k = tid >> 4, rm2 = tid & 15;
    float srow = 0.f;
    #pragma unroll 8
    for (int c2 = 0; c2 < 40; ++c2) srow += prow[k][rm2][c2];
    p_arr[(size_t)b * Kn + r0 + tid] = srow;
  }
  if (tid < Kn) {
    atomicAdd(&q_arr[(size_t)b * Kn + tid], qsh[tid]);
    atomicAdd(&vsc_arr[(size_t)b * Kn + tid], vsh[tid]);
  }
  if (tid == 0) {
    float sw = 0.f;
    #pragma unroll
    for (int i2 = 0; i2 < 10; ++i2) sw += wsh[i2];
    wpart[bid] = sw;
  }
}

// ---- gw1/gw2 over D_en/D_vi, float4, 2 blocks/batch; warms D for fgw_k.
// Even blocks (bid&1==0) also run the combine tail: span decode + QA CE +
// KL + span CE + w-sum. Cross-kernel deps: vsc/wpart from stats, wsl from qa.
__global__ __launch_bounds__(640) void dpass_k(
    const float* __restrict__ Den, const float* __restrict__ Dvi,
    const int* __restrict__ enst, const int* __restrict__ enen,
    const float* __restrict__ p_arr, const float* __restrict__ q_arr,
    const float* __restrict__ vsc_arr, const float* __restrict__ wpart,
    const float* __restrict__ wsl, float* __restrict__ g12part,
    float* __restrict__ sp1) {
  __shared__ float p_s[Kn];
  __shared__ float q_s[Kn];
  __shared__ float red[20];
  __shared__ float vsc_l[Kn];
  __shared__ float bv[256];
  __shared__ int bidx[256];
  __shared__ int pspe[2];
  int bid = blockIdx.x;
  int b = bid >> 1;
  int r0 = (bid & 1) * 80;
  int tid = threadIdx.x;
  int rm = tid / 40;
  int c = tid - 40 * rm;
  int wv = tid >> 6, lane = tid & 63;
  if (tid < Kn) {
    p_s[tid] = p_arr[(size_t)b * Kn + tid];
    q_s[tid] = q_arr[(size_t)b * Kn + tid];
  }
  __syncthreads();
  const float* db = Den + (size_t)b * Kn * Kn + (size_t)r0 * Kn;
  const float* vb = Dvi + (size_t)b * Kn * Kn + (size_t)r0 * Kn;
  float pc0 = p_s[4 * c], pc1 = p_s[4 * c + 1], pc2 = p_s[4 * c + 2], pc3 = p_s[4 * c + 3];
  float qc0 = q_s[4 * c], qc1 = q_s[4 * c + 1], qc2 = q_s[4 * c + 2], qc3 = q_s[4 * c + 3];
  float g1loc = 0.f, g2loc = 0.f;
  #pragma unroll
  for (int k = 0; k < 5; ++k) {
    int lr = 16 * k + rm;
    int i = r0 + lr;
    float4 d = *(const float4*)(db + (size_t)lr * Kn + 4 * c);
    g1loc += p_s[i] * (d.x*d.x*pc0 + d.y*d.y*pc1 + d.z*d.z*pc2 + d.w*d.w*pc3);
    float4 v = *(const float4*)(vb + (size_t)lr * Kn + 4 * c);
    g2loc += q_s[i] * (v.x*v.x*qc0 + v.y*v.y*qc1 + v.z*v.z*qc2 + v.w*v.w*qc3);
  }
  #pragma unroll
  for (int o = 32; o; o >>= 1) { g1loc += __shfl_xor(g1loc, o); g2loc += __shfl_xor(g2loc, o); }
  if (lane == 0) { red[wv] = g1loc; red[10 + wv] = g2loc; }
  __syncthreads();
  if (tid == 0) {
    float s1 = 0.f, s2 = 0.f;
    #pragma unroll
    for (int i = 0; i < 10; ++i) { s1 += red[i]; s2 += red[10 + i]; }
    g12part[(size_t)bid * 2] = s1;
    g12part[(size_t)bid * 2 + 1] = s2;
  }
  // ---- combine tail (even blocks only; uniform block-level branch) ----
  if ((bid & 1) != 0) return;
  int s0 = enst[b], e0 = enen[b];
  if (tid < Kn) vsc_l[tid] = vsc_arr[(size_t)b * Kn + tid];
  if (tid == 0)
    sp1[(size_t)b * 12 + 4] = wpart[2 * b] + wpart[2 * b + 1];
  __syncthreads();
  float best = -1e30f;
  int bfl = 0x7fffffff;
  if (tid < Kn) {
    float vsi = vsc_l[tid];
    int hi = min(tid + MAX_SPAN, Kn - 1);
    for (int ei = tid; ei <= hi; ++ei) {
      float v = vsi + vsc_l[ei];
      if (v > best) { best = v; bfl = tid * Kn + ei; }  // first-max (np.argmax)
    }
  }
  if (tid < 256) { bv[tid] = best; bidx[tid] = bfl; }
  for (int st = 128; st > 0; st >>= 1) {
    __syncthreads();
    if (tid < st) {
      float v2 = bv[tid + st]; int i2 = bidx[tid + st];
      if (v2 > bv[tid] || (v2 == bv[tid] && i2 < bidx[tid])) { bv[tid] = v2; bidx[tid] = i2; }
    }
  }
  if (tid == 0) {
    int fl = bidx[0];
    int ps = fl / Kn, pe = fl - (fl / Kn) * Kn;
    if (s0 == 0 && e0 == 0) { ps = 0; pe = 0; }
    pspe[0] = ps; pspe[1] = pe;
  }
  __syncthreads();
  if (wv == 0) {
    const float* es = wsl + (size_t)b * Kn;
    const float* ee = wsl + (size_t)BK + (size_t)b * Kn;
    const float* vs = wsl + (size_t)2 * BK + (size_t)b * Kn;
    const float* ve = wsl + (size_t)3 * BK + (size_t)b * Kn;
    float xes[3], xee[3], xvs[3], xve[3];
    #pragma unroll
    for (int j = 0; j < 3; ++j) {
      int idx = lane + 64 * j;
      bool val = idx < Kn;
      xes[j] = val ? es[idx] : -1e30f;
      xee[j] = val ? ee[idx] : -1e30f;
      xvs[j] = val ? vs[idx] : -1e30f;
      xve[j] = val ? ve[idx] : -1e30f;
    }
    auto wlse = [&](float x0, float x1, float x2) -> float {
      float m = fmaxf(fmaxf(x0, x1), x2);
      #pragma unroll
      for (int o = 32; o; o >>= 1) m = fmaxf(m, __shfl_xor(m, o));
      float su = expf(x0 - m) + expf(x1 - m) + expf(x2 - m);
      #pragma unroll
      for (int o = 32; o; o >>= 1) su += __shfl_xor(su, o);
      return m + logf(su);
    };
    float l_es = wlse(xes[0], xes[1], xes[2]);
    float l_ee = wlse(xee[0], xee[1], xee[2]);
    float l_vs = wlse(xvs[0], xvs[1], xvs[2]);
    float l_ve = wlse(xve[0], xve[1], xve[2]);
    float lT_es = wlse(xes[0]*0.5f, xes[1]*0.5f, xes[2]*0.5f);
    float lT_ee = wlse(xee[0]*0.5f, xee[1]*0.5f, xee[2]*0.5f);
    float lT_vs = wlse(xvs[0]*0.5f, xvs[1]*0.5f, xvs[2]*0.5f);
    float lT_ve = wlse(xve[0]*0.5f, xve[1]*0.5f, xve[2]*0.5f);
    float kls = 0.f, kle = 0.f;
    #pragma unroll
    for (int j = 0; j < 3; ++j) {
      int idx = lane + 64 * j;
      if (idx < Kn) {
        float aa = xes[j]*0.5f - lT_es;
        float bb = xvs[j]*0.5f - lT_vs;
        kls += expf(aa) * (aa - bb);
        float cc = xee[j]*0.5f - lT_ee;
        float dd = xve[j]*0.5f - lT_ve;
        kle += expf(cc) * (cc - dd);
      }
    }
    #pragma unroll
    for (int o = 32; o; o >>= 1) { kls += __shfl_xor(kls, o); kle += __shfl_xor(kle, o); }
    if (lane == 0) {
      int sl = min(max(s0, 0), Kn - 1);
      int el = min(max(e0, 0), Kn - 1);
      float* o = sp1 + (size_t)b * 12;
      o[0] = l_es - es[sl];
      o[1] = l_ee - ee[el];
      o[2] = kls;
      o[3] = kle;
      bool answerable = (s0 > 0) || (e0 > 0);
      float ce = 0.5f * ((l_vs - vs[pspe[0]]) + (l_ve - ve[pspe[1]]));
      o[5] = answerable ? ce : 0.f;
      o[6] = answerable ? 1.f : 0.f;
    }
  }
}

// ---- MFMA FGW, pure gw3; operands L3-warm (dpass streamed D, stats gamma).
// Software-pipelined, raw lgkm-only barriers. 2 blocks/batch (column halves). ----
__global__ __launch_bounds__(512) void fgw_k(
    const float* __restrict__ Den, const float* __restrict__ Dvi,
    const float* __restrict__ gam, float* __restrict__ sp2) {
  __shared__ __align__(16) __bf16 sDen[2][2][Kn][8];
  __shared__ __align__(16) __bf16 sG  [2][2][Kn][8];
  __shared__ __align__(16) __bf16 sGT [2][2][96][8];
  __shared__ __align__(16) __bf16 sVT [2][2][96][8];
  __shared__ float red[8];
  int bid = blockIdx.x;
  int h = (bid >> 3) & 1;
  int b = ((bid >> 4) << 3) | (bid & 7);
  const int JB = h ? 96 : 0;
  const int NBJ = h ? 64 : 96;
  const int NTJ = h ? 2 : 3;
  const int NT = 5 * NTJ;
  int tid = threadIdx.x;
  int wid = tid >> 6, lane = tid & 63;
  const float* den_b = Den + (size_t)b * Kn * Kn;
  const float* dvi_b = Dvi + (size_t)b * Kn * Kn;
  const float* gam_b = gam + (size_t)b * Kn * Kn;

  int op0 = tid >= 320 ? 1 : 0;
  int f0 = tid - 320 * op0;
  int c0 = f0 >= Kn ? 1 : 0;
  int r0 = f0 - Kn * c0;
  const float* s0p = (op0 ? gam_b : den_b) + (size_t)r0 * Kn + 8 * c0;
  __bf16* d00 = op0 ? &sG[0][c0][r0][0] : &sDen[0][c0][r0][0];
  __bf16* d01 = op0 ? &sG[1][c0][r0][0] : &sDen[1][c0][r0][0];
  bool rm1 = tid < 128;
  bool act1 = (tid + 512) < (640 + 4 * NBJ);
  const float* s1p = den_b;
  __bf16* d10 = &sGT[0][0][0][0];
  __bf16* d11 = &sGT[1][0][0][0];
  if (act1) {
    if (rm1) {
      int r1 = tid + 32;
      s1p = gam_b + (size_t)r1 * Kn + 8;
      d10 = &sG[0][1][r1][0];
      d11 = &sG[1][1][r1][0];
    } else {
      int f2 = tid - 128;
      int op1 = f2 >= 2 * NBJ ? 1 : 0;
      int f = f2 - 2 * NBJ * op1;
      int c1 = f >= NBJ ? 1 : 0;
      int r1 = f - NBJ * c1;
      int j = JB + r1;
      s1p = (op1 ? dvi_b : gam_b) + (size_t)(8 * c1) * Kn + j;
      d10 = op1 ? &sVT[0][c1][r1][0] : &sGT[0][c1][r1][0];
      d11 = op1 ? &sVT[1][c1][r1][0] : &sGT[1][c1][r1][0];
    }
  }
  float vA0[8], vA1[8], vB0[8], vB1[8];

  auto load0 = [&](int p, float* v) {
    const float* sp = s0p + p * KP;
    float4 x = *(const float4*)sp;
    float4 y = *(const float4*)(sp + 4);
    v[0]=x.x; v[1]=x.y; v[2]=x.z; v[3]=x.w;
    v[4]=y.x; v[5]=y.y; v[6]=y.z; v[7]=y.w;
  };
  auto load1 = [&](int p, float* v) {
    if (!act1) return;
    if (rm1) {
      const float* sp = s1p + p * KP;
      float4 x = *(const float4*)sp;
      float4 y = *(const float4*)(sp + 4);
      v[0]=x.x; v[1]=x.y; v[2]=x.z; v[3]=x.w;
      v[4]=y.x; v[5]=y.y; v[6]=y.z; v[7]=y.w;
    } else {
      const float* sp = s1p + (size_t)p * KP * Kn;
      #pragma unroll
      for (int e2 = 0; e2 < 8; ++e2) v[e2] = sp[(size_t)e2 * Kn];
    }
  };
  auto wr = [&](const float* v0, const float* v1, __bf16* w0, __bf16* w1) {
    bf16x8 wv;
    #pragma unroll
    for (int e2 = 0; e2 < 8; ++e2) wv[e2] = (__bf16)v0[e2];
    *(bf16x8*)w0 = wv;
    if (act1) {
      bf16x8 wv2;
      #pragma unroll
      for (int e2 = 0; e2 < 8; ++e2) wv2[e2] = (__bf16)v1[e2];
      *(bf16x8*)w1 = wv2;
    }
  };

  int ra = lane & 31, cc2 = lane >> 5;
  int t1i = wid + 8;
  bool val1t = t1i < NT;
  int ti0 = wid / NTJ, tj0 = wid - ti0 * NTJ;
  int rowa0 = ti0 * 32 + ra, rowb0 = tj0 * 32 + ra;
  int ti1 = t1i / NTJ, tj1 = t1i - ti1 * NTJ;
  int rowa1 = ti1 * 32 + ra, rowb1 = tj1 * 32 + ra;
  f32x16 acc10 = {}, acc20 = {}, acc11 = {}, acc21 = {};
  auto mf = [&](int BUF) {
    {
      bf16x8 a1 = *(const bf16x8*)&sDen[BUF][cc2][rowa0][0];
      bf16x8 b1 = *(const bf16x8*)&sGT[BUF][cc2][rowb0][0];
      bf16x8 a2 = *(const bf16x8*)&sG[BUF][cc2][rowa0][0];
      bf16x8 b2 = *(const bf16x8*)&sVT[BUF][cc2][rowb0][0];
      acc10 = __builtin_amdgcn_mfma_f32_32x32x16_bf16(a1, b1, acc10, 0, 0, 0);
      acc20 = __builtin_amdgcn_mfma_f32_32x32x16_bf16(a2, b2, acc20, 0, 0, 0);
    }
    if (val1t) {
      bf16x8 a1 = *(const bf16x8*)&sDen[BUF][cc2][rowa1][0];
      bf16x8 b1 = *(const bf16x8*)&sGT[BUF][cc2][rowb1][0];
      bf16x8 a2 = *(const bf16x8*)&sG[BUF][cc2][rowa1][0];
      bf16x8 b2 = *(const bf16x8*)&sVT[BUF][cc2][rowb1][0];
      acc11 = __builtin_amdgcn_mfma_f32_32x32x16_bf16(a1, b1, acc11, 0, 0, 0);
      acc21 = __builtin_amdgcn_mfma_f32_32x32x16_bf16(a2, b2, acc21, 0, 0, 0);
    }
  };

  load0(0, vA0); load1(0, vA1);
  load0(1, vB0); load1(1, vB1);
  wr(vA0, vA1, d00, d10);
  __syncthreads();
  for (int p = 0; p < NP; p += 2) {
    if (p + 2 < NP) { load0(p + 2, vA0); load1(p + 2, vA1); }
    mf(0);
    wr(vB0, vB1, d01, d11);
    wg_barrier();
    if (p + 3 < NP) { load0(p + 3, vB0); load1(p + 3, vB1); }
    mf(1);
    if (p + 2 < NP) wr(vA0, vA1, d00, d10);
    wg_barrier();
  }
  float g3 = 0.f;
  #pragma unroll
  for (int r2 = 0; r2 < 16; ++r2) g3 += acc10[r2] * acc20[r2];
  if (val1t) {
    #pragma unroll
    for (int r2 = 0; r2 < 16; ++r2) g3 += acc11[r2] * acc21[r2];
  }
  #pragma unroll
  for (int o = 32; o; o >>= 1) g3 += __shfl_xor(g3, o);
  if (lane == 0) red[wid] = g3;
  __syncthreads();
  if (tid == 0) {
    float s3 = 0.f;
    #pragma unroll
    for (int i = 0; i < 8; ++i) s3 += red[i];
    sp2[bid] = s3;
  }
}

// ---- final reduction of per-block slabs ----
__global__ __launch_bounds__(512) void finalize_k(
    const float* __restrict__ sp1, const float* __restrict__ sp2,
    const float* __restrict__ g12part, float* __restrict__ out) {
  __shared__ float red[8][10];
  int tid = threadIdx.x;
  int wid = tid >> 6, lane = tid & 63;
  float v[10];
  const float* a = sp1 + (size_t)tid * 12;
  #pragma unroll
  for (int i = 0; i < 7; ++i) v[i] = a[i];
  v[7] = g12part[4 * tid] + g12part[4 * tid + 2];
  v[8] = g12part[4 * tid + 1] + g12part[4 * tid + 3];
  v[9] = sp2[2 * tid] + sp2[2 * tid + 1];
  #pragma unroll
  for (int i = 0; i < 10; ++i) {
    float s = v[i];
    #pragma unroll
    for (int o = 32; o; o >>= 1) s += __shfl_xor(s, o);
    v[i] = s;
  }
  if (lane == 0) {
    #pragma unroll
    for (int i = 0; i < 10; ++i) red[wid][i] = v[i];
  }
  __syncthreads();
  if (tid == 0) {
    float t[10];
    #pragma unroll
    for (int i = 0; i < 10; ++i) {
      float s = 0.f;
      #pragma unroll
      for (int w2 = 0; w2 < 8; ++w2) s += red[w2][i];
      t[i] = s;
    }
    float ce_s = t[0], ce_e = t[1], kls = t[2], kle = t[3];
    float w = t[4], spn = t[5], nans = t[6];
    float gw1 = t[7], gw2 = t[8], gw3 = t[9];
    float l_qa = (ce_s + ce_e) / (2.f * Bn);
    float l_fgw = (ALPHA * (gw1 + gw2 - 2.f * gw3) + (1.f - ALPHA) * w) / Bn;
    float l_span = (nans > 0.f) ? spn / fmaxf(nans, 1.f) : 0.f;
    float l_cons = 2.f * (kls + kle) / Bn;  // T^2 * ((kls+kle)/B) / 2 with T=2
    float total = l_qa + L_FGW * l_fgw + L_SPAN * l_span + L_CONS * l_cons;
    out[0] = total; out[1] = l_qa; out[2] = l_fgw; out[3] = l_span; out[4] = l_cons;
  }
}

extern "C" void kernel_launch(void* const* d_in, const int* in_sizes, int n_in,
                              void* d_out, int out_size, void* d_ws, size_t ws_size,
                              hipStream_t stream) {
  const float* en  = (const float*)d_in[0];
  const float* vi  = (const float*)d_in[1];
  const float* gam = (const float*)d_in[2];
  const float* Den = (const float*)d_in[3];
  const float* Dvi = (const float*)d_in[4];
  const float* M   = (const float*)d_in[5];
  const int* enst  = (const int*)d_in[6];
  const int* enen  = (const int*)d_in[7];
  const float* w_s = (const float*)d_in[8];
  const float* b_s = (const float*)d_in[9];
  const float* w_e = (const float*)d_in[10];
  const float* b_e = (const float*)d_in[11];
  float* ws = (float*)d_ws;
  float* wsl = ws;                         // 4*BK logits
  float* p_arr = ws + (size_t)4 * BK;      // BK
  float* q_arr = p_arr + BK;               // BK (atomic-accumulated, zeroed by qa)
  float* vsc_arr = q_arr + BK;             // BK (atomic-accumulated, zeroed by qa)
  float* wpart = vsc_arr + BK;             // 1024
  float* sp1 = wpart + 1024;               // 512*12
  float* sp2 = sp1 + 12 * Bn;              // 1024
  float* g12part = sp2 + 1024;             // 1024*2
  float* out = (float*)d_out;

  qa_logits_k<<<(2 * BK) / 4, 256, 0, stream>>>(en, vi, w_s, b_s, w_e, b_e, wsl, q_arr);
  stats_part_k<<<2 * Bn, 640, 0, stream>>>(gam, M, enst, enen, p_arr, q_arr, vsc_arr, wpart);
  dpass_k<<<2 * Bn, 640, 0, stream>>>(Den, Dvi, enst, enen, p_arr, q_arr, vsc_arr,
                                      wpart, wsl, g12part, sp1);
  fgw_k<<<2 * Bn, 512, 0, stream>>>(Den, Dvi, gam, sp2);
  finalize_k<<<1, 512, 0, stream>>>(sp1, sp2, g12part, out);
}

// Round 15
// 118.168 us; speedup vs baseline: 1.3993x; 1.2851x over previous
//
#include <hip/hip_runtime.h>

#define Bn 512
#define Kn 160
#define Hn 256
#define ALPHA 0.5f
#define MAX_SPAN 30
#define L_FGW 0.1f
#define L_SPAN 0.5f
#define L_CONS 0.3f
#define KP 16
#define NP 10

typedef __bf16 bf16x8 __attribute__((ext_vector_type(8)));
typedef float f32x16 __attribute__((ext_vector_type(16)));
typedef float f32x4v __attribute__((ext_vector_type(4)));

// Phase A-D scratch (63.4 KB) and fgw scratch (41 KB) share one LDS union.
struct PhS {
  float prow[160][41];          // p row-partials (pad 41: conflict-free col sums)
  float qcol[25][160];          // q partials per row-group
  float vcol[25][160];          // vsc partials per row-group
  float psh[160], qsh[160], vscsh[160];
  float esh[160], eeh[160], vssh[160], veh[160];   // QA logits (in-LDS, no global)
  float wsh[16], g1sh[16], g2sh[16];
  float bv[256];
  int bidx[256];
  int pspe[2];
};
struct FgS {
  __bf16 sDen[2][2][Kn][8];
  __bf16 sG[2][2][Kn][8];
  __bf16 sGT[2][2][Kn][8];
  __bf16 sVT[2][2][Kn][8];
  float red[16];
};

// raw barrier: LDS drained, global loads stay in flight (no vmcnt drain)
__device__ __forceinline__ void wg_barrier() {
  asm volatile("s_waitcnt lgkmcnt(0)" ::: "memory");
  __builtin_amdgcn_s_barrier();
  __builtin_amdgcn_sched_barrier(0);
}

// ---- one block per batch: gamma/M stats -> D pass -> QA logits -> losses -> fgw ----
__global__ __launch_bounds__(1024, 4) void mega_k(
    const float* __restrict__ en, const float* __restrict__ vi,
    const float* __restrict__ w_s, const float* __restrict__ b_s,
    const float* __restrict__ w_e, const float* __restrict__ b_e,
    const float* __restrict__ gam, const float* __restrict__ M,
    const float* __restrict__ Den, const float* __restrict__ Dvi,
    const int* __restrict__ enst, const int* __restrict__ enen,
    float* __restrict__ sp1) {
  __shared__ __align__(16) char shraw[sizeof(PhS)];
  PhS& S = *(PhS*)shraw;
  FgS& F = *(FgS*)shraw;
  int b = blockIdx.x;
  int tid = threadIdx.x;
  int wv = tid >> 6, lane = tid & 63;
  const float* gam_b = gam + (size_t)b * 25600;
  const float* m_b   = M   + (size_t)b * 25600;
  const float* den_b = Den + (size_t)b * 25600;
  const float* dvi_b = Dvi + (size_t)b * 25600;
  int s0 = enst[b], e0 = enen[b];
  int s = min(max(s0, 0), Kn - 1);
  int e = max(s, min(max(e0, 0), Kn - 1));
  bool act = tid < 1000;
  int c = tid % 40, rg = tid / 40;   // fixed column group, 25 row-groups

  // ---- Phase A: gamma + M (M nontemporal; gamma stays for L3 re-read) ----
  float q4[4] = {0.f,0.f,0.f,0.f}, v4[4] = {0.f,0.f,0.f,0.f};
  float wloc = 0.f;
  #pragma unroll
  for (int i = 0; i < 7; ++i) {
    int r = rg + 25 * i;
    if (act && r < 160) {
      float4 g = *(const float4*)(gam_b + (size_t)r * 160 + 4 * c);
      f32x4v m = __builtin_nontemporal_load((const f32x4v*)(m_b + (size_t)r * 160 + 4 * c));
      wloc += m[0]*g.x + m[1]*g.y + m[2]*g.z + m[3]*g.w;
      S.prow[r][c] = g.x + g.y + g.z + g.w;
      q4[0]+=g.x; q4[1]+=g.y; q4[2]+=g.z; q4[3]+=g.w;
      float f = (r >= s && r <= e) ? 1.f : 0.f;
      v4[0]+=f*g.x; v4[1]+=f*g.y; v4[2]+=f*g.z; v4[3]+=f*g.w;
    }
  }
  if (act) {
    #pragma unroll
    for (int j = 0; j < 4; ++j) { S.qcol[rg][4*c+j] = q4[j]; S.vcol[rg][4*c+j] = v4[j]; }
  }
  #pragma unroll
  for (int o = 32; o; o >>= 1) wloc += __shfl_xor(wloc, o);
  if (lane == 0) S.wsh[wv] = wloc;
  __syncthreads();
  if (tid < 160) {
    float sp = 0.f;
    #pragma unroll 8
    for (int c2 = 0; c2 < 40; ++c2) sp += S.prow[tid][c2];
    S.psh[tid] = sp;
    float sq = 0.f, sv = 0.f;
    #pragma unroll 5
    for (int k = 0; k < 25; ++k) { sq += S.qcol[k][tid]; sv += S.vcol[k][tid]; }
    S.qsh[tid] = sq;
    S.vscsh[tid] = sv;
  }
  __syncthreads();

  // ---- Phase B: gw1/gw2 over D_en/D_vi (plain loads: fgw re-reads via L2/L3) ----
  float g1loc = 0.f, g2loc = 0.f;
  {
    float pc0=0,pc1=0,pc2=0,pc3=0,qc0=0,qc1=0,qc2=0,qc3=0;
    if (act) {
      pc0=S.psh[4*c]; pc1=S.psh[4*c+1]; pc2=S.psh[4*c+2]; pc3=S.psh[4*c+3];
      qc0=S.qsh[4*c]; qc1=S.qsh[4*c+1]; qc2=S.qsh[4*c+2]; qc3=S.qsh[4*c+3];
    }
    #pragma unroll
    for (int i = 0; i < 7; ++i) {
      int r = rg + 25 * i;
      if (act && r < 160) {
        float4 d = *(const float4*)(den_b + (size_t)r * 160 + 4 * c);
        g1loc += S.psh[r] * (d.x*d.x*pc0 + d.y*d.y*pc1 + d.z*d.z*pc2 + d.w*d.w*pc3);
        float4 v = *(const float4*)(dvi_b + (size_t)r * 160 + 4 * c);
        g2loc += S.qsh[r] * (v.x*v.x*qc0 + v.y*v.y*qc1 + v.z*v.z*qc2 + v.w*v.w*qc3);
      }
    }
  }
  #pragma unroll
  for (int o = 32; o; o >>= 1) { g1loc += __shfl_xor(g1loc, o); g2loc += __shfl_xor(g2loc, o); }
  if (lane == 0) { S.g1sh[wv] = g1loc; S.g2sh[wv] = g2loc; }

  // ---- Phase C: QA logits in-LDS (en/vi nontemporal, dead after) ----
  {
    float4 ws4 = *(const float4*)(w_s + lane * 4);
    float4 we4 = *(const float4*)(w_e + lane * 4);
    float bs0 = b_s[0], be0 = b_e[0];
    const float* en_b = en + (size_t)b * 40960;
    const float* vi_b = vi + (size_t)b * 40960;
    #pragma unroll
    for (int rr = 0; rr < 10; ++rr) {
      int row = wv * 10 + rr;
      f32x4v ev = __builtin_nontemporal_load((const f32x4v*)(en_b + (size_t)row * 256 + lane * 4));
      f32x4v vv = __builtin_nontemporal_load((const f32x4v*)(vi_b + (size_t)row * 256 + lane * 4));
      float a0 = ev[0]*ws4.x + ev[1]*ws4.y + ev[2]*ws4.z + ev[3]*ws4.w;
      float a1 = ev[0]*we4.x + ev[1]*we4.y + ev[2]*we4.z + ev[3]*we4.w;
      float a2 = vv[0]*ws4.x + vv[1]*ws4.y + vv[2]*ws4.z + vv[3]*ws4.w;
      float a3 = vv[0]*we4.x + vv[1]*we4.y + vv[2]*we4.z + vv[3]*we4.w;
      #pragma unroll
      for (int o = 32; o; o >>= 1) {
        a0 += __shfl_xor(a0, o); a1 += __shfl_xor(a1, o);
        a2 += __shfl_xor(a2, o); a3 += __shfl_xor(a3, o);
      }
      if (lane == 0) {
        S.esh[row] = a0 + bs0;  S.eeh[row] = a1 + be0;
        S.vssh[row] = a2 + bs0; S.veh[row] = a3 + be0;
      }
    }
  }
  __syncthreads();

  // ---- Phase D: span argmax + QA CE + KL + span CE -> sp1[0..8] ----
  float best = -1e30f;
  int bfl = 0x7fffffff;
  if (tid < 160) {
    float vsi = S.vscsh[tid];
    int hi = min(tid + MAX_SPAN, Kn - 1);
    for (int ei = tid; ei <= hi; ++ei) {
      float v = vsi + S.vscsh[ei];
      if (v > best) { best = v; bfl = tid * Kn + ei; }  // first-max (np.argmax)
    }
  }
  if (tid < 256) { S.bv[tid] = best; S.bidx[tid] = bfl; }
  for (int st = 128; st > 0; st >>= 1) {
    __syncthreads();
    if (tid < st) {
      float v2 = S.bv[tid + st]; int i2 = S.bidx[tid + st];
      if (v2 > S.bv[tid] || (v2 == S.bv[tid] && i2 < S.bidx[tid])) { S.bv[tid] = v2; S.bidx[tid] = i2; }
    }
  }
  if (tid == 0) {
    int fl = S.bidx[0];
    int ps = fl / Kn, pe = fl - (fl / Kn) * Kn;
    if (s0 == 0 && e0 == 0) { ps = 0; pe = 0; }
    S.pspe[0] = ps; S.pspe[1] = pe;
    float sw = 0.f, s1 = 0.f, s2 = 0.f;
    #pragma unroll
    for (int i = 0; i < 16; ++i) { sw += S.wsh[i]; s1 += S.g1sh[i]; s2 += S.g2sh[i]; }
    float* o = sp1 + (size_t)b * 12;
    o[4] = sw; o[7] = s1; o[8] = s2;
  }
  __syncthreads();
  if (wv == 0) {
    float xes[3], xee[3], xvs[3], xve[3];
    #pragma unroll
    for (int j = 0; j < 3; ++j) {
      int idx = lane + 64 * j;
      bool val = idx < Kn;
      xes[j] = val ? S.esh[idx] : -1e30f;
      xee[j] = val ? S.eeh[idx] : -1e30f;
      xvs[j] = val ? S.vssh[idx] : -1e30f;
      xve[j] = val ? S.veh[idx] : -1e30f;
    }
    auto wlse = [&](float x0, float x1, float x2) -> float {
      float m = fmaxf(fmaxf(x0, x1), x2);
      #pragma unroll
      for (int o = 32; o; o >>= 1) m = fmaxf(m, __shfl_xor(m, o));
      float su = expf(x0 - m) + expf(x1 - m) + expf(x2 - m);
      #pragma unroll
      for (int o = 32; o; o >>= 1) su += __shfl_xor(su, o);
      return m + logf(su);
    };
    float l_es = wlse(xes[0], xes[1], xes[2]);
    float l_ee = wlse(xee[0], xee[1], xee[2]);
    float l_vs = wlse(xvs[0], xvs[1], xvs[2]);
    float l_ve = wlse(xve[0], xve[1], xve[2]);
    float lT_es = wlse(xes[0]*0.5f, xes[1]*0.5f, xes[2]*0.5f);
    float lT_ee = wlse(xee[0]*0.5f, xee[1]*0.5f, xee[2]*0.5f);
    float lT_vs = wlse(xvs[0]*0.5f, xvs[1]*0.5f, xvs[2]*0.5f);
    float lT_ve = wlse(xve[0]*0.5f, xve[1]*0.5f, xve[2]*0.5f);
    float kls = 0.f, kle = 0.f;
    #pragma unroll
    for (int j = 0; j < 3; ++j) {
      int idx = lane + 64 * j;
      if (idx < Kn) {
        float aa = xes[j]*0.5f - lT_es;
        float bb = xvs[j]*0.5f - lT_vs;
        kls += expf(aa) * (aa - bb);
        float cc = xee[j]*0.5f - lT_ee;
        float dd = xve[j]*0.5f - lT_ve;
        kle += expf(cc) * (cc - dd);
      }
    }
    #pragma unroll
    for (int o = 32; o; o >>= 1) { kls += __shfl_xor(kls, o); kle += __shfl_xor(kle, o); }
    if (lane == 0) {
      int sl = min(max(s0, 0), Kn - 1);
      int el = min(max(e0, 0), Kn - 1);
      float* o = sp1 + (size_t)b * 12;
      o[0] = l_es - S.esh[sl];
      o[1] = l_ee - S.eeh[el];
      o[2] = kls;
      o[3] = kle;
      bool answerable = (s0 > 0) || (e0 > 0);
      float ce = 0.5f * ((l_vs - S.vssh[S.pspe[0]]) + (l_ve - S.veh[S.pspe[1]]));
      o[5] = answerable ? ce : 0.f;
      o[6] = answerable ? 1.f : 0.f;
    }
  }
  __syncthreads();   // all Phase-D LDS reads done before fgw overwrites the union

  // ---- Phase E: fgw gw3 via MFMA (operands L2/L3-warm from phases A/B) ----
  // slot0 (frag=tid): 0..319 sDen, 320..639 sG (row-major); 640..959 sGT,
  // 960..1023 sVT 0..63 (transposed). slot1 (tid<256): sVT 64..319.
  bool rm0 = tid < 640;
  const float* s0p;
  __bf16 *d00, *d01;
  if (rm0) {
    int op = tid >= 320 ? 1 : 0;
    int fr = tid - 320 * op;
    int cc = fr >= 160 ? 1 : 0;
    int r = fr - 160 * cc;
    s0p = (op ? gam_b : den_b) + (size_t)r * 160 + 8 * cc;
    d00 = op ? &F.sG[0][cc][r][0] : &F.sDen[0][cc][r][0];
    d01 = op ? &F.sG[1][cc][r][0] : &F.sDen[1][cc][r][0];
  } else {
    int f3 = tid - 640;
    int op = f3 >= 320 ? 1 : 0;
    int f4 = f3 - 320 * op;
    int cc = f4 >= 160 ? 1 : 0;
    int j = f4 - 160 * cc;
    s0p = (op ? dvi_b : gam_b) + (size_t)(8 * cc) * 160 + j;
    d00 = op ? &F.sVT[0][cc][j][0] : &F.sGT[0][cc][j][0];
    d01 = op ? &F.sVT[1][cc][j][0] : &F.sGT[1][cc][j][0];
  }
  bool act1 = tid < 256;
  int f5 = tid + 64;
  int cc1 = f5 >= 160 ? 1 : 0;
  int j1 = f5 - 160 * cc1;
  const float* s1p = dvi_b + (size_t)(8 * cc1) * 160 + j1;
  __bf16* d10 = &F.sVT[0][cc1][j1][0];
  __bf16* d11 = &F.sVT[1][cc1][j1][0];

  float vA0[8], vA1[8], vB0[8], vB1[8];
  auto load0 = [&](int p, float* v) {
    if (rm0) {
      const float* sp = s0p + p * KP;
      float4 x = *(const float4*)sp;
      float4 y = *(const float4*)(sp + 4);
      v[0]=x.x; v[1]=x.y; v[2]=x.z; v[3]=x.w;
      v[4]=y.x; v[5]=y.y; v[6]=y.z; v[7]=y.w;
    } else {
      const float* sp = s0p + (size_t)p * KP * 160;
      #pragma unroll
      for (int e2 = 0; e2 < 8; ++e2) v[e2] = sp[(size_t)e2 * 160];
    }
  };
  auto load1 = [&](int p, float* v) {
    if (!act1) return;
    const float* sp = s1p + (size_t)p * KP * 160;
    #pragma unroll
    for (int e2 = 0; e2 < 8; ++e2) v[e2] = sp[(size_t)e2 * 160];
  };
  auto wr = [&](const float* v0, const float* v1, __bf16* w0, __bf16* w1) {
    bf16x8 wv2;
    #pragma unroll
    for (int e2 = 0; e2 < 8; ++e2) wv2[e2] = (__bf16)v0[e2];
    *(bf16x8*)w0 = wv2;
    if (act1) {
      bf16x8 wv3;
      #pragma unroll
      for (int e2 = 0; e2 < 8; ++e2) wv3[e2] = (__bf16)v1[e2];
      *(bf16x8*)w1 = wv3;
    }
  };

  int ra = lane & 31, cc2 = lane >> 5;
  int t0 = wv;                 // 0..15, always < 25
  int ti0 = t0 / 5, tj0 = t0 - 5 * (t0 / 5);
  int rowa0 = ti0 * 32 + ra, rowb0 = tj0 * 32 + ra;
  int t1 = wv + 16;
  bool val1t = t1 < 25;
  int ti1 = t1 / 5, tj1 = t1 - 5 * (t1 / 5);
  int rowa1 = ti1 * 32 + ra, rowb1 = tj1 * 32 + ra;
  f32x16 acc10 = {}, acc20 = {}, acc11 = {}, acc21 = {};
  auto mf = [&](int BUF) {
    {
      bf16x8 a1 = *(const bf16x8*)&F.sDen[BUF][cc2][rowa0][0];
      bf16x8 b1 = *(const bf16x8*)&F.sGT[BUF][cc2][rowb0][0];
      bf16x8 a2 = *(const bf16x8*)&F.sG[BUF][cc2][rowa0][0];
      bf16x8 b2 = *(const bf16x8*)&F.sVT[BUF][cc2][rowb0][0];
      acc10 = __builtin_amdgcn_mfma_f32_32x32x16_bf16(a1, b1, acc10, 0, 0, 0);
      acc20 = __builtin_amdgcn_mfma_f32_32x32x16_bf16(a2, b2, acc20, 0, 0, 0);
    }
    if (val1t) {
      bf16x8 a1 = *(const bf16x8*)&F.sDen[BUF][cc2][rowa1][0];
      bf16x8 b1 = *(const bf16x8*)&F.sGT[BUF][cc2][rowb1][0];
      bf16x8 a2 = *(const bf16x8*)&F.sG[BUF][cc2][rowa1][0];
      bf16x8 b2 = *(const bf16x8*)&F.sVT[BUF][cc2][rowb1][0];
      acc11 = __builtin_amdgcn_mfma_f32_32x32x16_bf16(a1, b1, acc11, 0, 0, 0);
      acc21 = __builtin_amdgcn_mfma_f32_32x32x16_bf16(a2, b2, acc21, 0, 0, 0);
    }
  };

  load0(0, vA0); load1(0, vA1);
  load0(1, vB0); load1(1, vB1);
  wr(vA0, vA1, d00, d10);
  __syncthreads();
  for (int p = 0; p < NP; p += 2) {
    if (p + 2 < NP) { load0(p + 2, vA0); load1(p + 2, vA1); }
    mf(0);
    wr(vB0, vB1, d01, d11);
    wg_barrier();
    if (p + 3 < NP) { load0(p + 3, vB0); load1(p + 3, vB1); }
    mf(1);
    if (p + 2 < NP) wr(vA0, vA1, d00, d10);
    wg_barrier();
  }
  float g3 = 0.f;
  #pragma unroll
  for (int r2 = 0; r2 < 16; ++r2) g3 += acc10[r2] * acc20[r2];
  if (val1t) {
    #pragma unroll
    for (int r2 = 0; r2 < 16; ++r2) g3 += acc11[r2] * acc21[r2];
  }
  #pragma unroll
  for (int o = 32; o; o >>= 1) g3 += __shfl_xor(g3, o);
  if (lane == 0) F.red[wv] = g3;
  __syncthreads();
  if (tid == 0) {
    float s3 = 0.f;
    #pragma unroll
    for (int i = 0; i < 16; ++i) s3 += F.red[i];
    sp1[(size_t)b * 12 + 9] = s3;
  }
}

// ---- final reduction over batches ----
__global__ __launch_bounds__(512) void finalize_k(
    const float* __restrict__ sp1, float* __restrict__ out) {
  __shared__ float red[8][10];
  int tid = threadIdx.x;
  int wid = tid >> 6, lane = tid & 63;
  float v[10];
  const float* a = sp1 + (size_t)tid * 12;
  #pragma unroll
  for (int i = 0; i < 10; ++i) v[i] = a[i];
  #pragma unroll
  for (int i = 0; i < 10; ++i) {
    float s = v[i];
    #pragma unroll
    for (int o = 32; o; o >>= 1) s += __shfl_xor(s, o);
    v[i] = s;
  }
  if (lane == 0) {
    #pragma unroll
    for (int i = 0; i < 10; ++i) red[wid][i] = v[i];
  }
  __syncthreads();
  if (tid == 0) {
    float t[10];
    #pragma unroll
    for (int i = 0; i < 10; ++i) {
      float s = 0.f;
      #pragma unroll
      for (int w2 = 0; w2 < 8; ++w2) s += red[w2][i];
      t[i] = s;
    }
    float ce_s = t[0], ce_e = t[1], kls = t[2], kle = t[3];
    float w = t[4], spn = t[5], nans = t[6];
    float gw1 = t[7], gw2 = t[8], gw3 = t[9];
    float l_qa = (ce_s + ce_e) / (2.f * Bn);
    float l_fgw = (ALPHA * (gw1 + gw2 - 2.f * gw3) + (1.f - ALPHA) * w) / Bn;
    float l_span = (nans > 0.f) ? spn / fmaxf(nans, 1.f) : 0.f;
    float l_cons = 2.f * (kls + kle) / Bn;  // T^2 * ((kls+kle)/B) / 2 with T=2
    float total = l_qa + L_FGW * l_fgw + L_SPAN * l_span + L_CONS * l_cons;
    out[0] = total; out[1] = l_qa; out[2] = l_fgw; out[3] = l_span; out[4] = l_cons;
  }
}

extern "C" void kernel_launch(void* const* d_in, const int* in_sizes, int n_in,
                              void* d_out, int out_size, void* d_ws, size_t ws_size,
                              hipStream_t stream) {
  const float* en  = (const float*)d_in[0];
  const float* vi  = (const float*)d_in[1];
  const float* gam = (const float*)d_in[2];
  const float* Den = (const float*)d_in[3];
  const float* Dvi = (const float*)d_in[4];
  const float* M   = (const float*)d_in[5];
  const int* enst  = (const int*)d_in[6];
  const int* enen  = (const int*)d_in[7];
  const float* w_s = (const float*)d_in[8];
  const float* b_s = (const float*)d_in[9];
  const float* w_e = (const float*)d_in[10];
  const float* b_e = (const float*)d_in[11];
  float* sp1 = (float*)d_ws;               // 512*12 per-batch partials
  float* out = (float*)d_out;

  mega_k<<<Bn, 1024, 0, stream>>>(en, vi, w_s, b_s, w_e, b_e, gam, M, Den, Dvi,
                                  enst, enen, sp1);
  finalize_k<<<1, 512, 0, stream>>>(sp1, out);
}

// Round 16
// 109.757 us; speedup vs baseline: 1.5065x; 1.0766x over previous
//
#include <hip/hip_runtime.h>

#define Bn 512
#define Kn 160
#define Hn 256
#define ALPHA 0.5f
#define MAX_SPAN 30
#define L_FGW 0.1f
#define L_SPAN 0.5f
#define L_CONS 0.3f
#define KP 16
#define NP 10

typedef __bf16 bf16x8 __attribute__((ext_vector_type(8)));
typedef float f32x16 __attribute__((ext_vector_type(16)));
typedef float f32x4v __attribute__((ext_vector_type(4)));

// Phase A-D scratch (~53 KB) and fgw scratch (41 KB) share one LDS union.
struct PhS {
  float prow[160][41];          // p row-partials (pad 41)
  float qcol[16][160];          // q partials per rm
  float vcol[16][160];          // vsc partials per rm
  float psh[160], qsh[160], vscsh[160];
  float esh[160], eeh[160], vssh[160], veh[160];   // QA logits in-LDS
  float wsh[16], g1sh[16], g2sh[16];
  float bv[256];
  int bidx[256];
  int pspe[2];
};
struct FgS {
  __bf16 sDen[2][2][Kn][8];
  __bf16 sG[2][2][Kn][8];
  __bf16 sGT[2][2][Kn][8];
  __bf16 sVT[2][2][Kn][8];
  float red[16];
};

// raw barrier: LDS drained, global loads stay in flight (no vmcnt drain)
__device__ __forceinline__ void wg_barrier() {
  asm volatile("s_waitcnt lgkmcnt(0)" ::: "memory");
  __builtin_amdgcn_s_barrier();
  __builtin_amdgcn_sched_barrier(0);
}

// ---- one block per batch: fused gamma/M + QA streams -> D pass -> losses -> fgw ----
__global__ __launch_bounds__(1024, 4) void mega_k(
    const float* __restrict__ en, const float* __restrict__ vi,
    const float* __restrict__ w_s, const float* __restrict__ b_s,
    const float* __restrict__ w_e, const float* __restrict__ b_e,
    const float* __restrict__ gam, const float* __restrict__ M,
    const float* __restrict__ Den, const float* __restrict__ Dvi,
    const int* __restrict__ enst, const int* __restrict__ enen,
    float* __restrict__ sp1) {
  __shared__ __align__(16) char shraw[sizeof(PhS)];
  PhS& S = *(PhS*)shraw;
  FgS& F = *(FgS*)shraw;
  int b = blockIdx.x;
  int tid = threadIdx.x;
  int wv = tid >> 6, lane = tid & 63;
  const float* gam_b = gam + (size_t)b * 25600;
  const float* m_b   = M   + (size_t)b * 25600;
  const float* den_b = Den + (size_t)b * 25600;
  const float* dvi_b = Dvi + (size_t)b * 25600;
  int s0 = enst[b], e0 = enen[b];
  int s = min(max(s0, 0), Kn - 1);
  int e = max(s, min(max(e0, 0), Kn - 1));
  bool actA = tid < 640;
  int rm = tid / 40, c = tid - 40 * rm;    // A/B layout (uniform 16-row slabs)

  // ---- Phase A+C fused: gamma+M stats and QA logits in one 10-iter loop ----
  float4 ws4 = *(const float4*)(w_s + lane * 4);
  float4 we4 = *(const float4*)(w_e + lane * 4);
  float bs0 = b_s[0], be0 = b_e[0];
  const float* en_b = en + (size_t)b * 40960;
  const float* vi_b = vi + (size_t)b * 40960;
  float q4[4] = {0.f,0.f,0.f,0.f}, v4[4] = {0.f,0.f,0.f,0.f};
  float wloc = 0.f;
  #pragma unroll
  for (int it = 0; it < 10; ++it) {
    int crow = wv * 10 + it;     // C: one row per wave per iter
    f32x4v ev = __builtin_nontemporal_load((const f32x4v*)(en_b + (size_t)crow * 256 + lane * 4));
    f32x4v vv = __builtin_nontemporal_load((const f32x4v*)(vi_b + (size_t)crow * 256 + lane * 4));
    if (actA) {
      int r = 16 * it + rm;      // A: uniform 16-row slab
      float4 g = *(const float4*)(gam_b + (size_t)r * 160 + 4 * c);
      f32x4v m = __builtin_nontemporal_load((const f32x4v*)(m_b + (size_t)r * 160 + 4 * c));
      wloc += m[0]*g.x + m[1]*g.y + m[2]*g.z + m[3]*g.w;
      S.prow[r][c] = g.x + g.y + g.z + g.w;
      q4[0]+=g.x; q4[1]+=g.y; q4[2]+=g.z; q4[3]+=g.w;
      float f = (r >= s && r <= e) ? 1.f : 0.f;
      v4[0]+=f*g.x; v4[1]+=f*g.y; v4[2]+=f*g.z; v4[3]+=f*g.w;
    }
    float a0 = ev[0]*ws4.x + ev[1]*ws4.y + ev[2]*ws4.z + ev[3]*ws4.w;
    float a1 = ev[0]*we4.x + ev[1]*we4.y + ev[2]*we4.z + ev[3]*we4.w;
    float a2 = vv[0]*ws4.x + vv[1]*ws4.y + vv[2]*ws4.z + vv[3]*ws4.w;
    float a3 = vv[0]*we4.x + vv[1]*we4.y + vv[2]*we4.z + vv[3]*we4.w;
    #pragma unroll
    for (int o = 32; o; o >>= 1) {
      a0 += __shfl_xor(a0, o); a1 += __shfl_xor(a1, o);
      a2 += __shfl_xor(a2, o); a3 += __shfl_xor(a3, o);
    }
    if (lane == 0) {
      S.esh[crow] = a0 + bs0;  S.eeh[crow] = a1 + be0;
      S.vssh[crow] = a2 + bs0; S.veh[crow] = a3 + be0;
    }
  }
  if (actA) {
    #pragma unroll
    for (int j = 0; j < 4; ++j) { S.qcol[rm][4*c+j] = q4[j]; S.vcol[rm][4*c+j] = v4[j]; }
  }
  #pragma unroll
  for (int o = 32; o; o >>= 1) wloc += __shfl_xor(wloc, o);
  if (lane == 0) S.wsh[wv] = wloc;
  __syncthreads();
  if (tid < 160) {
    float sp = 0.f;
    #pragma unroll 8
    for (int c2 = 0; c2 < 40; ++c2) sp += S.prow[tid][c2];
    S.psh[tid] = sp;
    float sq = 0.f, sv = 0.f;
    #pragma unroll 4
    for (int k = 0; k < 16; ++k) { sq += S.qcol[k][tid]; sv += S.vcol[k][tid]; }
    S.qsh[tid] = sq;
    S.vscsh[tid] = sv;
  }
  __syncthreads();

  // ---- Phase B: gw1/gw2 over D_en/D_vi (uniform slabs; warms D for E) ----
  float g1loc = 0.f, g2loc = 0.f;
  if (actA) {
    float pc0=S.psh[4*c], pc1=S.psh[4*c+1], pc2=S.psh[4*c+2], pc3=S.psh[4*c+3];
    float qc0=S.qsh[4*c], qc1=S.qsh[4*c+1], qc2=S.qsh[4*c+2], qc3=S.qsh[4*c+3];
    #pragma unroll
    for (int k = 0; k < 10; ++k) {
      int r = 16 * k + rm;
      float4 d = *(const float4*)(den_b + (size_t)r * 160 + 4 * c);
      g1loc += S.psh[r] * (d.x*d.x*pc0 + d.y*d.y*pc1 + d.z*d.z*pc2 + d.w*d.w*pc3);
      float4 v = *(const float4*)(dvi_b + (size_t)r * 160 + 4 * c);
      g2loc += S.qsh[r] * (v.x*v.x*qc0 + v.y*v.y*qc1 + v.z*v.z*qc2 + v.w*v.w*qc3);
    }
  }
  #pragma unroll
  for (int o = 32; o; o >>= 1) { g1loc += __shfl_xor(g1loc, o); g2loc += __shfl_xor(g2loc, o); }
  if (lane == 0) { S.g1sh[wv] = g1loc; S.g2sh[wv] = g2loc; }
  __syncthreads();

  // ---- Phase D: span argmax + QA CE + KL + span CE -> sp1[0..8] ----
  float best = -1e30f;
  int bfl = 0x7fffffff;
  if (tid < 160) {
    float vsi = S.vscsh[tid];
    int hi = min(tid + MAX_SPAN, Kn - 1);
    for (int ei = tid; ei <= hi; ++ei) {
      float v = vsi + S.vscsh[ei];
      if (v > best) { best = v; bfl = tid * Kn + ei; }  // first-max (np.argmax)
    }
  }
  if (tid < 256) { S.bv[tid] = best; S.bidx[tid] = bfl; }
  for (int st = 128; st > 0; st >>= 1) {
    __syncthreads();
    if (tid < st) {
      float v2 = S.bv[tid + st]; int i2 = S.bidx[tid + st];
      if (v2 > S.bv[tid] || (v2 == S.bv[tid] && i2 < S.bidx[tid])) { S.bv[tid] = v2; S.bidx[tid] = i2; }
    }
  }
  if (tid == 0) {
    int fl = S.bidx[0];
    int ps = fl / Kn, pe = fl - (fl / Kn) * Kn;
    if (s0 == 0 && e0 == 0) { ps = 0; pe = 0; }
    S.pspe[0] = ps; S.pspe[1] = pe;
    float sw = 0.f, s1 = 0.f, s2 = 0.f;
    #pragma unroll
    for (int i = 0; i < 16; ++i) { sw += S.wsh[i]; s1 += S.g1sh[i]; s2 += S.g2sh[i]; }
    float* o = sp1 + (size_t)b * 12;
    o[4] = sw; o[7] = s1; o[8] = s2;
  }
  __syncthreads();
  if (wv == 0) {
    float xes[3], xee[3], xvs[3], xve[3];
    #pragma unroll
    for (int j = 0; j < 3; ++j) {
      int idx = lane + 64 * j;
      bool val = idx < Kn;
      xes[j] = val ? S.esh[idx] : -1e30f;
      xee[j] = val ? S.eeh[idx] : -1e30f;
      xvs[j] = val ? S.vssh[idx] : -1e30f;
      xve[j] = val ? S.veh[idx] : -1e30f;
    }
    auto wlse = [&](float x0, float x1, float x2) -> float {
      float m = fmaxf(fmaxf(x0, x1), x2);
      #pragma unroll
      for (int o = 32; o; o >>= 1) m = fmaxf(m, __shfl_xor(m, o));
      float su = expf(x0 - m) + expf(x1 - m) + expf(x2 - m);
      #pragma unroll
      for (int o = 32; o; o >>= 1) su += __shfl_xor(su, o);
      return m + logf(su);
    };
    float l_es = wlse(xes[0], xes[1], xes[2]);
    float l_ee = wlse(xee[0], xee[1], xee[2]);
    float l_vs = wlse(xvs[0], xvs[1], xvs[2]);
    float l_ve = wlse(xve[0], xve[1], xve[2]);
    float lT_es = wlse(xes[0]*0.5f, xes[1]*0.5f, xes[2]*0.5f);
    float lT_ee = wlse(xee[0]*0.5f, xee[1]*0.5f, xee[2]*0.5f);
    float lT_vs = wlse(xvs[0]*0.5f, xvs[1]*0.5f, xvs[2]*0.5f);
    float lT_ve = wlse(xve[0]*0.5f, xve[1]*0.5f, xve[2]*0.5f);
    float kls = 0.f, kle = 0.f;
    #pragma unroll
    for (int j = 0; j < 3; ++j) {
      int idx = lane + 64 * j;
      if (idx < Kn) {
        float aa = xes[j]*0.5f - lT_es;
        float bb = xvs[j]*0.5f - lT_vs;
        kls += expf(aa) * (aa - bb);
        float cc = xee[j]*0.5f - lT_ee;
        float dd = xve[j]*0.5f - lT_ve;
        kle += expf(cc) * (cc - dd);
      }
    }
    #pragma unroll
    for (int o = 32; o; o >>= 1) { kls += __shfl_xor(kls, o); kle += __shfl_xor(kle, o); }
    if (lane == 0) {
      int sl = min(max(s0, 0), Kn - 1);
      int el = min(max(e0, 0), Kn - 1);
      float* o = sp1 + (size_t)b * 12;
      o[0] = l_es - S.esh[sl];
      o[1] = l_ee - S.eeh[el];
      o[2] = kls;
      o[3] = kle;
      bool answerable = (s0 > 0) || (e0 > 0);
      float ce = 0.5f * ((l_vs - S.vssh[S.pspe[0]]) + (l_ve - S.veh[S.pspe[1]]));
      o[5] = answerable ? ce : 0.f;
      o[6] = answerable ? 1.f : 0.f;
    }
  }
  __syncthreads();   // all Phase-D LDS reads done before fgw overwrites the union

  // ---- Phase E: fgw gw3 via MFMA (operands L2/L3-warm from phases A/B) ----
  bool rm0 = tid < 640;
  const float* s0p;
  __bf16 *d00, *d01;
  if (rm0) {
    int op = tid >= 320 ? 1 : 0;
    int fr = tid - 320 * op;
    int cc = fr >= 160 ? 1 : 0;
    int r = fr - 160 * cc;
    s0p = (op ? gam_b : den_b) + (size_t)r * 160 + 8 * cc;
    d00 = op ? &F.sG[0][cc][r][0] : &F.sDen[0][cc][r][0];
    d01 = op ? &F.sG[1][cc][r][0] : &F.sDen[1][cc][r][0];
  } else {
    int f3 = tid - 640;
    int op = f3 >= 320 ? 1 : 0;
    int f4 = f3 - 320 * op;
    int cc = f4 >= 160 ? 1 : 0;
    int j = f4 - 160 * cc;
    s0p = (op ? dvi_b : gam_b) + (size_t)(8 * cc) * 160 + j;
    d00 = op ? &F.sVT[0][cc][j][0] : &F.sGT[0][cc][j][0];
    d01 = op ? &F.sVT[1][cc][j][0] : &F.sGT[1][cc][j][0];
  }
  bool act1 = tid < 256;
  int f5 = tid + 64;
  int cc1 = f5 >= 160 ? 1 : 0;
  int j1 = f5 - 160 * cc1;
  const float* s1p = dvi_b + (size_t)(8 * cc1) * 160 + j1;
  __bf16* d10 = &F.sVT[0][cc1][j1][0];
  __bf16* d11 = &F.sVT[1][cc1][j1][0];

  float vA0[8], vA1[8], vB0[8], vB1[8];
  auto load0 = [&](int p, float* v) {
    if (rm0) {
      const float* sp = s0p + p * KP;
      float4 x = *(const float4*)sp;
      float4 y = *(const float4*)(sp + 4);
      v[0]=x.x; v[1]=x.y; v[2]=x.z; v[3]=x.w;
      v[4]=y.x; v[5]=y.y; v[6]=y.z; v[7]=y.w;
    } else {
      const float* sp = s0p + (size_t)p * KP * 160;
      #pragma unroll
      for (int e2 = 0; e2 < 8; ++e2) v[e2] = sp[(size_t)e2 * 160];
    }
  };
  auto load1 = [&](int p, float* v) {
    if (!act1) return;
    const float* sp = s1p + (size_t)p * KP * 160;
    #pragma unroll
    for (int e2 = 0; e2 < 8; ++e2) v[e2] = sp[(size_t)e2 * 160];
  };
  auto wr = [&](const float* v0, const float* v1, __bf16* w0, __bf16* w1) {
    bf16x8 wv2;
    #pragma unroll
    for (int e2 = 0; e2 < 8; ++e2) wv2[e2] = (__bf16)v0[e2];
    *(bf16x8*)w0 = wv2;
    if (act1) {
      bf16x8 wv3;
      #pragma unroll
      for (int e2 = 0; e2 < 8; ++e2) wv3[e2] = (__bf16)v1[e2];
      *(bf16x8*)w1 = wv3;
    }
  };

  int ra = lane & 31, cc2 = lane >> 5;
  int t0 = wv;                 // 0..15, always < 25
  int ti0 = t0 / 5, tj0 = t0 - 5 * (t0 / 5);
  int rowa0 = ti0 * 32 + ra, rowb0 = tj0 * 32 + ra;
  int t1 = wv + 16;
  bool val1t = t1 < 25;
  int ti1 = t1 / 5, tj1 = t1 - 5 * (t1 / 5);
  int rowa1 = ti1 * 32 + ra, rowb1 = tj1 * 32 + ra;
  f32x16 acc10 = {}, acc20 = {}, acc11 = {}, acc21 = {};
  auto mf = [&](int BUF) {
    {
      bf16x8 a1 = *(const bf16x8*)&F.sDen[BUF][cc2][rowa0][0];
      bf16x8 b1 = *(const bf16x8*)&F.sGT[BUF][cc2][rowb0][0];
      bf16x8 a2 = *(const bf16x8*)&F.sG[BUF][cc2][rowa0][0];
      bf16x8 b2 = *(const bf16x8*)&F.sVT[BUF][cc2][rowb0][0];
      acc10 = __builtin_amdgcn_mfma_f32_32x32x16_bf16(a1, b1, acc10, 0, 0, 0);
      acc20 = __builtin_amdgcn_mfma_f32_32x32x16_bf16(a2, b2, acc20, 0, 0, 0);
    }
    if (val1t) {
      bf16x8 a1 = *(const bf16x8*)&F.sDen[BUF][cc2][rowa1][0];
      bf16x8 b1 = *(const bf16x8*)&F.sGT[BUF][cc2][rowb1][0];
      bf16x8 a2 = *(const bf16x8*)&F.sG[BUF][cc2][rowa1][0];
      bf16x8 b2 = *(const bf16x8*)&F.sVT[BUF][cc2][rowb1][0];
      acc11 = __builtin_amdgcn_mfma_f32_32x32x16_bf16(a1, b1, acc11, 0, 0, 0);
      acc21 = __builtin_amdgcn_mfma_f32_32x32x16_bf16(a2, b2, acc21, 0, 0, 0);
    }
  };

  load0(0, vA0); load1(0, vA1);
  load0(1, vB0); load1(1, vB1);
  wr(vA0, vA1, d00, d10);
  __syncthreads();
  for (int p = 0; p < NP; p += 2) {
    if (p + 2 < NP) { load0(p + 2, vA0); load1(p + 2, vA1); }
    mf(0);
    wr(vB0, vB1, d01, d11);
    wg_barrier();
    if (p + 3 < NP) { load0(p + 3, vB0); load1(p + 3, vB1); }
    mf(1);
    if (p + 2 < NP) wr(vA0, vA1, d00, d10);
    wg_barrier();
  }
  float g3 = 0.f;
  #pragma unroll
  for (int r2 = 0; r2 < 16; ++r2) g3 += acc10[r2] * acc20[r2];
  if (val1t) {
    #pragma unroll
    for (int r2 = 0; r2 < 16; ++r2) g3 += acc11[r2] * acc21[r2];
  }
  #pragma unroll
  for (int o = 32; o; o >>= 1) g3 += __shfl_xor(g3, o);
  if (lane == 0) F.red[wv] = g3;
  __syncthreads();
  if (tid == 0) {
    float s3 = 0.f;
    #pragma unroll
    for (int i = 0; i < 16; ++i) s3 += F.red[i];
    sp1[(size_t)b * 12 + 9] = s3;
  }
}

// ---- final reduction over batches ----
__global__ __launch_bounds__(512) void finalize_k(
    const float* __restrict__ sp1, float* __restrict__ out) {
  __shared__ float red[8][10];
  int tid = threadIdx.x;
  int wid = tid >> 6, lane = tid & 63;
  float v[10];
  const float* a = sp1 + (size_t)tid * 12;
  #pragma unroll
  for (int i = 0; i < 10; ++i) v[i] = a[i];
  #pragma unroll
  for (int i = 0; i < 10; ++i) {
    float s = v[i];
    #pragma unroll
    for (int o = 32; o; o >>= 1) s += __shfl_xor(s, o);
    v[i] = s;
  }
  if (lane == 0) {
    #pragma unroll
    for (int i = 0; i < 10; ++i) red[wid][i] = v[i];
  }
  __syncthreads();
  if (tid == 0) {
    float t[10];
    #pragma unroll
    for (int i = 0; i < 10; ++i) {
      float s = 0.f;
      #pragma unroll
      for (int w2 = 0; w2 < 8; ++w2) s += red[w2][i];
      t[i] = s;
    }
    float ce_s = t[0], ce_e = t[1], kls = t[2], kle = t[3];
    float w = t[4], spn = t[5], nans = t[6];
    float gw1 = t[7], gw2 = t[8], gw3 = t[9];
    float l_qa = (ce_s + ce_e) / (2.f * Bn);
    float l_fgw = (ALPHA * (gw1 + gw2 - 2.f * gw3) + (1.f - ALPHA) * w) / Bn;
    float l_span = (nans > 0.f) ? spn / fmaxf(nans, 1.f) : 0.f;
    float l_cons = 2.f * (kls + kle) / Bn;  // T^2 * ((kls+kle)/B) / 2 with T=2
    float total = l_qa + L_FGW * l_fgw + L_SPAN * l_span + L_CONS * l_cons;
    out[0] = total; out[1] = l_qa; out[2] = l_fgw; out[3] = l_span; out[4] = l_cons;
  }
}

extern "C" void kernel_launch(void* const* d_in, const int* in_sizes, int n_in,
                              void* d_out, int out_size, void* d_ws, size_t ws_size,
                              hipStream_t stream) {
  const float* en  = (const float*)d_in[0];
  const float* vi  = (const float*)d_in[1];
  const float* gam = (const float*)d_in[2];
  const float* Den = (const float*)d_in[3];
  const float* Dvi = (const float*)d_in[4];
  const float* M   = (const float*)d_in[5];
  const int* enst  = (const int*)d_in[6];
  const int* enen  = (const int*)d_in[7];
  const float* w_s = (const float*)d_in[8];
  const float* b_s = (const float*)d_in[9];
  const float* w_e = (const float*)d_in[10];
  const float* b_e = (const float*)d_in[11];
  float* sp1 = (float*)d_ws;               // 512*12 per-batch partials
  float* out = (float*)d_out;

  mega_k<<<Bn, 1024, 0, stream>>>(en, vi, w_s, b_s, w_e, b_e, gam, M, Den, Dvi,
                                  enst, enen, sp1);
  finalize_k<<<1, 512, 0, stream>>>(sp1, out);
}

// Round 17
// 108.988 us; speedup vs baseline: 1.5172x; 1.0071x over previous
//
#include <hip/hip_runtime.h>

#define Bn 512
#define Kn 160
#define Hn 256
#define ALPHA 0.5f
#define MAX_SPAN 30
#define L_FGW 0.1f
#define L_SPAN 0.5f
#define L_CONS 0.3f
#define KP 16
#define NP 10

typedef __bf16 bf16x8 __attribute__((ext_vector_type(8)));
typedef float f32x16 __attribute__((ext_vector_type(16)));
typedef float f32x4v __attribute__((ext_vector_type(4)));

// Phase A-D scratch and fgw scratch share one LDS union; p/q live OUTSIDE
// the union (E's gw1/gw2 fusion reads them during MFMA staging).
struct PhS {
  float prow[160][41];          // p row-partials (pad 41)
  float qcol[16][160];          // q partials per rm
  float vcol[16][160];          // vsc partials per rm
  float vscsh[160];
  float esh[160], eeh[160], vssh[160], veh[160];   // QA logits in-LDS
  float wsh[16];
  float bv[256];
  int bidx[256];
  int pspe[2];
};
struct FgS {
  __bf16 sDen[2][2][Kn][8];
  __bf16 sG[2][2][Kn][8];
  __bf16 sGT[2][2][Kn][8];
  __bf16 sVT[2][2][Kn][8];
  float red[48];
};

// raw barrier: LDS drained, global loads stay in flight (no vmcnt drain)
__device__ __forceinline__ void wg_barrier() {
  asm volatile("s_waitcnt lgkmcnt(0)" ::: "memory");
  __builtin_amdgcn_s_barrier();
  __builtin_amdgcn_sched_barrier(0);
}

// ---- one block per batch: fused gamma/M + QA streams -> losses -> fgw(+gw1/gw2) ----
__global__ __launch_bounds__(1024, 4) void mega_k(
    const float* __restrict__ en, const float* __restrict__ vi,
    const float* __restrict__ w_s, const float* __restrict__ b_s,
    const float* __restrict__ w_e, const float* __restrict__ b_e,
    const float* __restrict__ gam, const float* __restrict__ M,
    const float* __restrict__ Den, const float* __restrict__ Dvi,
    const int* __restrict__ enst, const int* __restrict__ enen,
    float* __restrict__ sp1) {
  __shared__ __align__(16) char shraw[sizeof(PhS)];
  __shared__ float psh_s[160];
  __shared__ float qsh_s[160];
  PhS& S = *(PhS*)shraw;
  FgS& F = *(FgS*)shraw;
  int b = blockIdx.x;
  int tid = threadIdx.x;
  int wv = tid >> 6, lane = tid & 63;
  const float* gam_b = gam + (size_t)b * 25600;
  const float* m_b   = M   + (size_t)b * 25600;
  const float* den_b = Den + (size_t)b * 25600;
  const float* dvi_b = Dvi + (size_t)b * 25600;
  int s0 = enst[b], e0 = enen[b];
  int s = min(max(s0, 0), Kn - 1);
  int e = max(s, min(max(e0, 0), Kn - 1));
  bool actA = tid < 640;
  int rm = tid / 40, c = tid - 40 * rm;    // A layout (uniform 16-row slabs)

  // ---- Phase A+C fused: gamma+M stats and QA logits in one 10-iter loop ----
  float4 ws4 = *(const float4*)(w_s + lane * 4);
  float4 we4 = *(const float4*)(w_e + lane * 4);
  float bs0 = b_s[0], be0 = b_e[0];
  const float* en_b = en + (size_t)b * 40960;
  const float* vi_b = vi + (size_t)b * 40960;
  float q4[4] = {0.f,0.f,0.f,0.f}, v4[4] = {0.f,0.f,0.f,0.f};
  float wloc = 0.f;
  #pragma unroll
  for (int it = 0; it < 10; ++it) {
    int crow = wv * 10 + it;     // C: one row per wave per iter
    f32x4v ev = __builtin_nontemporal_load((const f32x4v*)(en_b + (size_t)crow * 256 + lane * 4));
    f32x4v vv = __builtin_nontemporal_load((const f32x4v*)(vi_b + (size_t)crow * 256 + lane * 4));
    if (actA) {
      int r = 16 * it + rm;      // A: uniform 16-row slab
      float4 g = *(const float4*)(gam_b + (size_t)r * 160 + 4 * c);
      f32x4v m = __builtin_nontemporal_load((const f32x4v*)(m_b + (size_t)r * 160 + 4 * c));
      wloc += m[0]*g.x + m[1]*g.y + m[2]*g.z + m[3]*g.w;
      S.prow[r][c] = g.x + g.y + g.z + g.w;
      q4[0]+=g.x; q4[1]+=g.y; q4[2]+=g.z; q4[3]+=g.w;
      float f = (r >= s && r <= e) ? 1.f : 0.f;
      v4[0]+=f*g.x; v4[1]+=f*g.y; v4[2]+=f*g.z; v4[3]+=f*g.w;
    }
    float a0 = ev[0]*ws4.x + ev[1]*ws4.y + ev[2]*ws4.z + ev[3]*ws4.w;
    float a1 = ev[0]*we4.x + ev[1]*we4.y + ev[2]*we4.z + ev[3]*we4.w;
    float a2 = vv[0]*ws4.x + vv[1]*ws4.y + vv[2]*ws4.z + vv[3]*ws4.w;
    float a3 = vv[0]*we4.x + vv[1]*we4.y + vv[2]*we4.z + vv[3]*we4.w;
    #pragma unroll
    for (int o = 32; o; o >>= 1) {
      a0 += __shfl_xor(a0, o); a1 += __shfl_xor(a1, o);
      a2 += __shfl_xor(a2, o); a3 += __shfl_xor(a3, o);
    }
    if (lane == 0) {
      S.esh[crow] = a0 + bs0;  S.eeh[crow] = a1 + be0;
      S.vssh[crow] = a2 + bs0; S.veh[crow] = a3 + be0;
    }
  }
  if (actA) {
    #pragma unroll
    for (int j = 0; j < 4; ++j) { S.qcol[rm][4*c+j] = q4[j]; S.vcol[rm][4*c+j] = v4[j]; }
  }
  #pragma unroll
  for (int o = 32; o; o >>= 1) wloc += __shfl_xor(wloc, o);
  if (lane == 0) S.wsh[wv] = wloc;
  __syncthreads();
  if (tid < 160) {
    float sp = 0.f;
    #pragma unroll 8
    for (int c2 = 0; c2 < 40; ++c2) sp += S.prow[tid][c2];
    psh_s[tid] = sp;
    float sq = 0.f, sv = 0.f;
    #pragma unroll 4
    for (int k = 0; k < 16; ++k) { sq += S.qcol[k][tid]; sv += S.vcol[k][tid]; }
    qsh_s[tid] = sq;
    S.vscsh[tid] = sv;
  }
  __syncthreads();

  // ---- Phase D: span argmax + QA CE + KL + span CE -> sp1[0..6] ----
  float best = -1e30f;
  int bfl = 0x7fffffff;
  if (tid < 160) {
    float vsi = S.vscsh[tid];
    int hi = min(tid + MAX_SPAN, Kn - 1);
    for (int ei = tid; ei <= hi; ++ei) {
      float v = vsi + S.vscsh[ei];
      if (v > best) { best = v; bfl = tid * Kn + ei; }  // first-max (np.argmax)
    }
  }
  if (tid < 256) { S.bv[tid] = best; S.bidx[tid] = bfl; }
  for (int st = 128; st > 0; st >>= 1) {
    __syncthreads();
    if (tid < st) {
      float v2 = S.bv[tid + st]; int i2 = S.bidx[tid + st];
      if (v2 > S.bv[tid] || (v2 == S.bv[tid] && i2 < S.bidx[tid])) { S.bv[tid] = v2; S.bidx[tid] = i2; }
    }
  }
  if (tid == 0) {
    int fl = S.bidx[0];
    int ps = fl / Kn, pe = fl - (fl / Kn) * Kn;
    if (s0 == 0 && e0 == 0) { ps = 0; pe = 0; }
    S.pspe[0] = ps; S.pspe[1] = pe;
    float sw = 0.f;
    #pragma unroll
    for (int i = 0; i < 16; ++i) sw += S.wsh[i];
    sp1[(size_t)b * 12 + 4] = sw;
  }
  __syncthreads();
  if (wv == 0) {
    float xes[3], xee[3], xvs[3], xve[3];
    #pragma unroll
    for (int j = 0; j < 3; ++j) {
      int idx = lane + 64 * j;
      bool val = idx < Kn;
      xes[j] = val ? S.esh[idx] : -1e30f;
      xee[j] = val ? S.eeh[idx] : -1e30f;
      xvs[j] = val ? S.vssh[idx] : -1e30f;
      xve[j] = val ? S.veh[idx] : -1e30f;
    }
    auto wlse = [&](float x0, float x1, float x2) -> float {
      float m = fmaxf(fmaxf(x0, x1), x2);
      #pragma unroll
      for (int o = 32; o; o >>= 1) m = fmaxf(m, __shfl_xor(m, o));
      float su = expf(x0 - m) + expf(x1 - m) + expf(x2 - m);
      #pragma unroll
      for (int o = 32; o; o >>= 1) su += __shfl_xor(su, o);
      return m + logf(su);
    };
    float l_es = wlse(xes[0], xes[1], xes[2]);
    float l_ee = wlse(xee[0], xee[1], xee[2]);
    float l_vs = wlse(xvs[0], xvs[1], xvs[2]);
    float l_ve = wlse(xve[0], xve[1], xve[2]);
    float lT_es = wlse(xes[0]*0.5f, xes[1]*0.5f, xes[2]*0.5f);
    float lT_ee = wlse(xee[0]*0.5f, xee[1]*0.5f, xee[2]*0.5f);
    float lT_vs = wlse(xvs[0]*0.5f, xvs[1]*0.5f, xvs[2]*0.5f);
    float lT_ve = wlse(xve[0]*0.5f, xve[1]*0.5f, xve[2]*0.5f);
    float kls = 0.f, kle = 0.f;
    #pragma unroll
    for (int j = 0; j < 3; ++j) {
      int idx = lane + 64 * j;
      if (idx < Kn) {
        float aa = xes[j]*0.5f - lT_es;
        float bb = xvs[j]*0.5f - lT_vs;
        kls += expf(aa) * (aa - bb);
        float cc = xee[j]*0.5f - lT_ee;
        float dd = xve[j]*0.5f - lT_ve;
        kle += expf(cc) * (cc - dd);
      }
    }
    #pragma unroll
    for (int o = 32; o; o >>= 1) { kls += __shfl_xor(kls, o); kle += __shfl_xor(kle, o); }
    if (lane == 0) {
      int sl = min(max(s0, 0), Kn - 1);
      int el = min(max(e0, 0), Kn - 1);
      float* o = sp1 + (size_t)b * 12;
      o[0] = l_es - S.esh[sl];
      o[1] = l_ee - S.eeh[el];
      o[2] = kls;
      o[3] = kle;
      bool answerable = (s0 > 0) || (e0 > 0);
      float ce = 0.5f * ((l_vs - S.vssh[S.pspe[0]]) + (l_ve - S.veh[S.pspe[1]]));
      o[5] = answerable ? ce : 0.f;
      o[6] = answerable ? 1.f : 0.f;
    }
  }
  __syncthreads();   // all Phase-D LDS reads done before fgw overwrites the union

  // ---- Phase E: fgw gw3 via MFMA; gw1/gw2 fused into the staging loads
  // (each D_en/D_vi element passes through exactly once, fp32, pre-bf16).
  bool rm0 = tid < 640;
  const float* s0p;
  __bf16 *d00, *d01;
  bool isDen0 = false, isVT0 = false;
  float w0r = 0.f;       // p[r] for D_en threads, q[j] for slot0-VT threads
  int cb0 = 0;           // 8*cc: column base within panel
  if (rm0) {
    int op = tid >= 320 ? 1 : 0;
    int fr = tid - 320 * op;
    int cc = fr >= 160 ? 1 : 0;
    int r = fr - 160 * cc;
    s0p = (op ? gam_b : den_b) + (size_t)r * 160 + 8 * cc;
    d00 = op ? &F.sG[0][cc][r][0] : &F.sDen[0][cc][r][0];
    d01 = op ? &F.sG[1][cc][r][0] : &F.sDen[1][cc][r][0];
    if (!op) { isDen0 = true; w0r = psh_s[r]; cb0 = 8 * cc; }
  } else {
    int f3 = tid - 640;
    int op = f3 >= 320 ? 1 : 0;
    int f4 = f3 - 320 * op;
    int cc = f4 >= 160 ? 1 : 0;
    int j = f4 - 160 * cc;
    s0p = (op ? dvi_b : gam_b) + (size_t)(8 * cc) * 160 + j;
    d00 = op ? &F.sVT[0][cc][j][0] : &F.sGT[0][cc][j][0];
    d01 = op ? &F.sVT[1][cc][j][0] : &F.sGT[1][cc][j][0];
    if (op) { isVT0 = true; w0r = qsh_s[j]; cb0 = 8 * cc; }
  }
  bool act1 = tid < 256;
  int f5 = tid + 64;
  int cc1 = f5 >= 160 ? 1 : 0;
  int j1 = f5 - 160 * cc1;
  const float* s1p = dvi_b + (size_t)(8 * cc1) * 160 + j1;
  __bf16* d10 = &F.sVT[0][cc1][j1][0];
  __bf16* d11 = &F.sVT[1][cc1][j1][0];
  float w1r = act1 ? qsh_s[j1] : 0.f;
  int cb1 = 8 * cc1;
  float gw1a = 0.f, gw2a = 0.f;

  float vA0[8], vA1[8], vB0[8], vB1[8];
  auto load0 = [&](int p, float* v) {
    if (rm0) {
      const float* sp = s0p + p * KP;
      float4 x = *(const float4*)sp;
      float4 y = *(const float4*)(sp + 4);
      v[0]=x.x; v[1]=x.y; v[2]=x.z; v[3]=x.w;
      v[4]=y.x; v[5]=y.y; v[6]=y.z; v[7]=y.w;
      if (isDen0) {
        const float* pw = psh_s + cb0 + 16 * p;
        float t = 0.f;
        #pragma unroll
        for (int e2 = 0; e2 < 8; ++e2) t += v[e2] * v[e2] * pw[e2];
        gw1a += w0r * t;
      }
    } else {
      const float* sp = s0p + (size_t)p * KP * 160;
      #pragma unroll
      for (int e2 = 0; e2 < 8; ++e2) v[e2] = sp[(size_t)e2 * 160];
      if (isVT0) {
        const float* qw = qsh_s + cb0 + 16 * p;
        float t = 0.f;
        #pragma unroll
        for (int e2 = 0; e2 < 8; ++e2) t += v[e2] * v[e2] * qw[e2];
        gw2a += w0r * t;
      }
    }
  };
  auto load1 = [&](int p, float* v) {
    if (!act1) return;
    const float* sp = s1p + (size_t)p * KP * 160;
    #pragma unroll
    for (int e2 = 0; e2 < 8; ++e2) v[e2] = sp[(size_t)e2 * 160];
    const float* qw = qsh_s + cb1 + 16 * p;
    float t = 0.f;
    #pragma unroll
    for (int e2 = 0; e2 < 8; ++e2) t += v[e2] * v[e2] * qw[e2];
    gw2a += w1r * t;
  };
  auto wr = [&](const float* v0, const float* v1, __bf16* w0, __bf16* w1) {
    bf16x8 wv2;
    #pragma unroll
    for (int e2 = 0; e2 < 8; ++e2) wv2[e2] = (__bf16)v0[e2];
    *(bf16x8*)w0 = wv2;
    if (act1) {
      bf16x8 wv3;
      #pragma unroll
      for (int e2 = 0; e2 < 8; ++e2) wv3[e2] = (__bf16)v1[e2];
      *(bf16x8*)w1 = wv3;
    }
  };

  int ra = lane & 31, cc2 = lane >> 5;
  int t0 = wv;                 // 0..15, always < 25
  int ti0 = t0 / 5, tj0 = t0 - 5 * (t0 / 5);
  int rowa0 = ti0 * 32 + ra, rowb0 = tj0 * 32 + ra;
  int t1 = wv + 16;
  bool val1t = t1 < 25;
  int ti1 = t1 / 5, tj1 = t1 - 5 * (t1 / 5);
  int rowa1 = ti1 * 32 + ra, rowb1 = tj1 * 32 + ra;
  f32x16 acc10 = {}, acc20 = {}, acc11 = {}, acc21 = {};
  auto mf = [&](int BUF) {
    {
      bf16x8 a1 = *(const bf16x8*)&F.sDen[BUF][cc2][rowa0][0];
      bf16x8 b1 = *(const bf16x8*)&F.sGT[BUF][cc2][rowb0][0];
      bf16x8 a2 = *(const bf16x8*)&F.sG[BUF][cc2][rowa0][0];
      bf16x8 b2 = *(const bf16x8*)&F.sVT[BUF][cc2][rowb0][0];
      acc10 = __builtin_amdgcn_mfma_f32_32x32x16_bf16(a1, b1, acc10, 0, 0, 0);
      acc20 = __builtin_amdgcn_mfma_f32_32x32x16_bf16(a2, b2, acc20, 0, 0, 0);
    }
    if (val1t) {
      bf16x8 a1 = *(const bf16x8*)&F.sDen[BUF][cc2][rowa1][0];
      bf16x8 b1 = *(const bf16x8*)&F.sGT[BUF][cc2][rowb1][0];
      bf16x8 a2 = *(const bf16x8*)&F.sG[BUF][cc2][rowa1][0];
      bf16x8 b2 = *(const bf16x8*)&F.sVT[BUF][cc2][rowb1][0];
      acc11 = __builtin_amdgcn_mfma_f32_32x32x16_bf16(a1, b1, acc11, 0, 0, 0);
      acc21 = __builtin_amdgcn_mfma_f32_32x32x16_bf16(a2, b2, acc21, 0, 0, 0);
    }
  };

  load0(0, vA0); load1(0, vA1);
  load0(1, vB0); load1(1, vB1);
  wr(vA0, vA1, d00, d10);
  __syncthreads();
  for (int p = 0; p < NP; p += 2) {
    if (p + 2 < NP) { load0(p + 2, vA0); load1(p + 2, vA1); }
    mf(0);
    wr(vB0, vB1, d01, d11);
    wg_barrier();
    if (p + 3 < NP) { load0(p + 3, vB0); load1(p + 3, vB1); }
    mf(1);
    if (p + 2 < NP) wr(vA0, vA1, d00, d10);
    wg_barrier();
  }
  float g3 = 0.f;
  #pragma unroll
  for (int r2 = 0; r2 < 16; ++r2) g3 += acc10[r2] * acc20[r2];
  if (val1t) {
    #pragma unroll
    for (int r2 = 0; r2 < 16; ++r2) g3 += acc11[r2] * acc21[r2];
  }
  #pragma unroll
  for (int o = 32; o; o >>= 1) {
    g3 += __shfl_xor(g3, o);
    gw1a += __shfl_xor(gw1a, o);
    gw2a += __shfl_xor(gw2a, o);
  }
  if (lane == 0) { F.red[wv] = g3; F.red[16 + wv] = gw1a; F.red[32 + wv] = gw2a; }
  __syncthreads();
  if (tid == 0) {
    float s3 = 0.f, s1 = 0.f, s2 = 0.f;
    #pragma unroll
    for (int i = 0; i < 16; ++i) { s3 += F.red[i]; s1 += F.red[16 + i]; s2 += F.red[32 + i]; }
    float* o = sp1 + (size_t)b * 12;
    o[7] = s1; o[8] = s2; o[9] = s3;
  }
}

// ---- final reduction over batches ----
__global__ __launch_bounds__(512) void finalize_k(
    const float* __restrict__ sp1, float* __restrict__ out) {
  __shared__ float red[8][10];
  int tid = threadIdx.x;
  int wid = tid >> 6, lane = tid & 63;
  float v[10];
  const float* a = sp1 + (size_t)tid * 12;
  #pragma unroll
  for (int i = 0; i < 10; ++i) v[i] = a[i];
  #pragma unroll
  for (int i = 0; i < 10; ++i) {
    float s = v[i];
    #pragma unroll
    for (int o = 32; o; o >>= 1) s += __shfl_xor(s, o);
    v[i] = s;
  }
  if (lane == 0) {
    #pragma unroll
    for (int i = 0; i < 10; ++i) red[wid][i] = v[i];
  }
  __syncthreads();
  if (tid == 0) {
    float t[10];
    #pragma unroll
    for (int i = 0; i < 10; ++i) {
      float s = 0.f;
      #pragma unroll
      for (int w2 = 0; w2 < 8; ++w2) s += red[w2][i];
      t[i] = s;
    }
    float ce_s = t[0], ce_e = t[1], kls = t[2], kle = t[3];
    float w = t[4], spn = t[5], nans = t[6];
    float gw1 = t[7], gw2 = t[8], gw3 = t[9];
    float l_qa = (ce_s + ce_e) / (2.f * Bn);
    float l_fgw = (ALPHA * (gw1 + gw2 - 2.f * gw3) + (1.f - ALPHA) * w) / Bn;
    float l_span = (nans > 0.f) ? spn / fmaxf(nans, 1.f) : 0.f;
    float l_cons = 2.f * (kls + kle) / Bn;  // T^2 * ((kls+kle)/B) / 2 with T=2
    float total = l_qa + L_FGW * l_fgw + L_SPAN * l_span + L_CONS * l_cons;
    out[0] = total; out[1] = l_qa; out[2] = l_fgw; out[3] = l_span; out[4] = l_cons;
  }
}

extern "C" void kernel_launch(void* const* d_in, const int* in_sizes, int n_in,
                              void* d_out, int out_size, void* d_ws, size_t ws_size,
                              hipStream_t stream) {
  const float* en  = (const float*)d_in[0];
  const float* vi  = (const float*)d_in[1];
  const float* gam = (const float*)d_in[2];
  const float* Den = (const float*)d_in[3];
  const float* Dvi = (const float*)d_in[4];
  const float* M   = (const float*)d_in[5];
  const int* enst  = (const int*)d_in[6];
  const int* enen  = (const int*)d_in[7];
  const float* w_s = (const float*)d_in[8];
  const float* b_s = (const float*)d_in[9];
  const float* w_e = (const float*)d_in[10];
  const float* b_e = (const float*)d_in[11];
  float* sp1 = (float*)d_ws;               // 512*12 per-batch partials
  float* out = (float*)d_out;

  mega_k<<<Bn, 1024, 0, stream>>>(en, vi, w_s, b_s, w_e, b_e, gam, M, Den, Dvi,
                                  enst, enen, sp1);
  finalize_k<<<1, 512, 0, stream>>>(sp1, out);
}